// Round 1
// baseline (955.849 us; speedup 1.0000x reference)
//
#include <hip/hip_runtime.h>
#include <cstddef>

// Voxel encoder: B=2, N=16384, G=512 voxels x K=32 pts, d=128, S=2 layers.
// Pipeline: qkv GEMM (layer0, gathered) -> per-voxel attention -> qkv GEMM
// (layer1) -> attention -> fused trans GEMM + LN + ReLU + maxpool + scatter.
// All fp32. Bias trick: bias[i,j] = k_i . enc[i,j] decomposed into
// dk[i][axis*50+l] = k_i . table_axis[l] (small GEMM) + 3 scalar lookups,
// avoiding 1.5MB/group of table gathers.

#define D_   128
#define VSF  0.25f
#define QSF  0.01f
#define LQ   50
#define G_   512
#define KP   32
#define BB   2
#define NP   16384
#define MT   32768          // B*N rows
#define SCALE 0.08838834764831845f   // 1/sqrt(128)

// ---------------------------------------------------------------------------
// QKV projection: out[m, 0:384] = F_gathered[m, 0:128] @ W[128,384] + bias.
// Tile: 64 rows x 128 cols per block, K-chunks of 16 staged in LDS.
// grid = (512, 3), block = 256.
// ---------------------------------------------------------------------------
__global__ __launch_bounds__(256) void qkv_gemm(
    const float* __restrict__ F, const int* __restrict__ groups,
    const float* __restrict__ W, const float* __restrict__ bias,
    float* __restrict__ out)
{
  __shared__ __align__(16) float A_s[16][68];   // [k][row], padded
  __shared__ __align__(16) float B_s[16][132];  // [k][col], padded
  const int t  = threadIdx.x;
  const int m0 = blockIdx.x * 64;
  const int n0 = blockIdx.y * 128;

  // A-load mapping: thread -> (row r, k-quad kq)
  const int r  = t >> 2;
  const int kq = (t & 3) * 4;
  const int m  = m0 + r;
  const float* arow;
  if (groups) {
    const int b   = m >> 14;
    const int pid = groups[m];
    arow = F + ((size_t)(b << 14) + (size_t)pid) * D_;
  } else {
    arow = F + (size_t)m * D_;
  }
  // B-load mapping
  const int kkb = t >> 4;
  const int cb  = (t & 15) * 8;
  const float* wbase = W + (size_t)kkb * 384 + n0 + cb;
  // compute mapping: 8 rows x 4 cols per thread
  const int tx = t & 31, ty = t >> 5;

  float acc[8][4];
  #pragma unroll
  for (int i = 0; i < 8; i++)
    #pragma unroll
    for (int j = 0; j < 4; j++) acc[i][j] = 0.f;

  for (int k0 = 0; k0 < D_; k0 += 16) {
    float4 av = *(const float4*)(arow + k0 + kq);
    float4 b0 = *(const float4*)(wbase + (size_t)k0 * 384);
    float4 b1 = *(const float4*)(wbase + (size_t)k0 * 384 + 4);
    __syncthreads();
    A_s[kq + 0][r] = av.x;
    A_s[kq + 1][r] = av.y;
    A_s[kq + 2][r] = av.z;
    A_s[kq + 3][r] = av.w;
    *(float4*)&B_s[kkb][cb]     = b0;
    *(float4*)&B_s[kkb][cb + 4] = b1;
    __syncthreads();
    #pragma unroll
    for (int kk = 0; kk < 16; kk++) {
      float4 a03 = *(const float4*)&A_s[kk][ty * 8];
      float4 a47 = *(const float4*)&A_s[kk][ty * 8 + 4];
      float4 bv  = *(const float4*)&B_s[kk][tx * 4];
      float a[8] = {a03.x, a03.y, a03.z, a03.w, a47.x, a47.y, a47.z, a47.w};
      float bj[4] = {bv.x, bv.y, bv.z, bv.w};
      #pragma unroll
      for (int i = 0; i < 8; i++)
        #pragma unroll
        for (int j = 0; j < 4; j++)
          acc[i][j] += a[i] * bj[j];
    }
  }
  float4 bsv = *(const float4*)(bias + n0 + tx * 4);
  #pragma unroll
  for (int i = 0; i < 8; i++) {
    float4 o;
    o.x = acc[i][0] + bsv.x; o.y = acc[i][1] + bsv.y;
    o.z = acc[i][2] + bsv.z; o.w = acc[i][3] + bsv.w;
    *(float4*)(out + (size_t)(m0 + ty * 8 + i) * 384 + n0 + tx * 4) = o;
  }
}

// ---------------------------------------------------------------------------
// Per-voxel attention. One block per (b,g). q,k staged in LDS; v read from
// global (L1-resident, 16KB/block). dk[i][150] precomputed in LDS.
// grid = 1024, block = 256.
// ---------------------------------------------------------------------------
__global__ __launch_bounds__(256) void attn_kernel(
    const float* __restrict__ qkv,     // [MT, 384]
    const float* __restrict__ coords,  // [B, N, 3]
    const int*   __restrict__ groups,  // [B*N]
    const float* __restrict__ tbl_x, const float* __restrict__ tbl_y,
    const float* __restrict__ tbl_z,
    int s,
    float* __restrict__ fout)          // [MT, 128]
{
  __shared__ __align__(16) float qk_s[32][260];  // cols 0:128 q, 128:256 k
  __shared__ float dk_s[32 * 153];
  __shared__ float sc_s[32 * 33];
  __shared__ float cs[32][3];

  const int t   = threadIdx.x;
  const int bid = blockIdx.x;
  const int b   = bid >> 9;
  const int g   = bid & 511;
  const size_t mbase = (size_t)bid * 32;

  // stage q,k: 32 rows x 256 cols
  {
    const int p = t >> 3, seg = t & 7;
    const float* src = qkv + (mbase + p) * 384 + seg * 32;
    float* dst = &qk_s[p][seg * 32];
    #pragma unroll
    for (int u = 0; u < 8; u++)
      *(float4*)(dst + u * 4) = *(const float4*)(src + u * 4);
  }
  if (t < 32) {
    const int pid = groups[(b << 14) + g * KP + t];
    const float* cp = coords + ((size_t)(b << 14) + (size_t)pid) * 3;
    cs[t][0] = cp[0]; cs[t][1] = cp[1]; cs[t][2] = cp[2];
  }
  __syncthreads();

  // dk phase: dk[i][c] = k_i . table_{c/50}[s,1,c%50,:]
  {
    const int i = t >> 3, c0 = t & 7;
    const size_t toff = ((size_t)s * 3 + 1) * (LQ * D_);
    const float* kr = &qk_s[i][128];
    for (int it = 0; it < 19; it++) {
      const int c = c0 + it * 8;
      if (c < 150) {
        const int axis = c / 50, l = c - axis * 50;
        const float* tb = (axis == 0 ? tbl_x : (axis == 1 ? tbl_y : tbl_z))
                          + toff + (size_t)l * D_;
        float4 a4 = {0.f, 0.f, 0.f, 0.f};
        #pragma unroll
        for (int d = 0; d < D_; d += 4) {
          float4 kv = *(const float4*)(kr + d);
          float4 tv = *(const float4*)(tb + d);
          a4.x += kv.x * tv.x; a4.y += kv.y * tv.y;
          a4.z += kv.z * tv.z; a4.w += kv.w * tv.w;
        }
        dk_s[i * 153 + c] = a4.x + a4.y + a4.z + a4.w;
      }
    }
  }
  __syncthreads();

  // scores: s[i,j] = (q_i.k_j + dk lookups) * SCALE
  {
    const int i = t >> 3, j0 = t & 7;
    const float cix = cs[i][0], ciy = cs[i][1], ciz = cs[i][2];
    const float* qi  = &qk_s[i][0];
    const float* dki = &dk_s[i * 153];
    #pragma unroll
    for (int jt = 0; jt < 4; jt++) {
      const int j = j0 + jt * 8;
      const float* kj = &qk_s[j][128];
      float4 a4 = {0.f, 0.f, 0.f, 0.f};
      #pragma unroll
      for (int d = 0; d < D_; d += 4) {
        float4 qv = *(const float4*)(qi + d);
        float4 kv = *(const float4*)(kj + d);
        a4.x += qv.x * kv.x; a4.y += qv.y * kv.y;
        a4.z += qv.z * kv.z; a4.w += qv.w * kv.w;
      }
      const float dot = a4.x + a4.y + a4.z + a4.w;
      float dx = cix - cs[j][0], dy = ciy - cs[j][1], dz = ciz - cs[j][2];
      int ix = (int)floorf((dx + VSF) / QSF);
      int iy = (int)floorf((dy + VSF) / QSF);
      int iz = (int)floorf((dz + VSF) / QSF);
      ix = ix < 0 ? 0 : (ix > 49 ? 49 : ix);
      iy = iy < 0 ? 0 : (iy > 49 ? 49 : iy);
      iz = iz < 0 ? 0 : (iz > 49 ? 49 : iz);
      const float biasv = dki[ix] + dki[50 + iy] + dki[100 + iz];
      sc_s[i * 33 + j] = (dot + biasv) * SCALE;
    }
  }
  __syncthreads();

  // softmax over each row (32 threads, one row each)
  if (t < 32) {
    float* row = &sc_s[t * 33];
    float mx = row[0];
    #pragma unroll
    for (int j = 1; j < 32; j++) mx = fmaxf(mx, row[j]);
    float sum = 0.f;
    #pragma unroll
    for (int j = 0; j < 32; j++) { float e = __expf(row[j] - mx); row[j] = e; sum += e; }
    const float inv = 1.f / sum;
    #pragma unroll
    for (int j = 0; j < 32; j++) row[j] *= inv;
  }
  __syncthreads();

  // PV: f[i, es:es+16] = sum_j attn[i,j] * v[j, es:es+16]; v from global
  {
    const int i = t >> 3, es = (t & 7) * 16;
    const float* vbase = qkv + mbase * 384 + 256 + es;
    float4 acc0 = {0,0,0,0}, acc1 = {0,0,0,0}, acc2 = {0,0,0,0}, acc3 = {0,0,0,0};
    for (int j = 0; j < 32; j++) {
      const float a = sc_s[i * 33 + j];
      const float* vr = vbase + (size_t)j * 384;
      float4 v0 = *(const float4*)(vr);
      float4 v1 = *(const float4*)(vr + 4);
      float4 v2 = *(const float4*)(vr + 8);
      float4 v3 = *(const float4*)(vr + 12);
      acc0.x += a * v0.x; acc0.y += a * v0.y; acc0.z += a * v0.z; acc0.w += a * v0.w;
      acc1.x += a * v1.x; acc1.y += a * v1.y; acc1.z += a * v1.z; acc1.w += a * v1.w;
      acc2.x += a * v2.x; acc2.y += a * v2.y; acc2.z += a * v2.z; acc2.w += a * v2.w;
      acc3.x += a * v3.x; acc3.y += a * v3.y; acc3.z += a * v3.z; acc3.w += a * v3.w;
    }
    float* dst = fout + (mbase + i) * D_ + es;
    *(float4*)(dst + 0)  = acc0;
    *(float4*)(dst + 4)  = acc1;
    *(float4*)(dst + 8)  = acc2;
    *(float4*)(dst + 12) = acc3;
  }
}

// ---------------------------------------------------------------------------
// Fused epilogue: x=[feats|f1|f2] (staged), h = x@W + b, LayerNorm, ReLU,
// maxpool over 32 points, write grid-reordered `out` + per-point scatter.
// One block per (b,g). grid = 1024, block = 256.
// ---------------------------------------------------------------------------
__global__ __launch_bounds__(256) void trans_kernel(
    const float* __restrict__ inputs, const int* __restrict__ groups,
    const float* __restrict__ f1, const float* __restrict__ f2,
    const float* __restrict__ W,      // [384,128]
    const float* __restrict__ bias,   // [128]
    const float* __restrict__ ln_g, const float* __restrict__ ln_b,
    float* __restrict__ out_all)
{
  __shared__ __align__(16) float x_s[32][388];   // reused as h[32][132] later
  __shared__ __align__(16) float Wc[16][132];
  __shared__ float pooled[128];

  const int t   = threadIdx.x;
  const int bid = blockIdx.x;
  const int b   = bid >> 9;
  const int g   = bid & 511;
  const size_t mbase = (size_t)bid * 32;

  // stage x = [feats(gathered) | f1 | f2]
  {
    const int p = t >> 3, seg = t & 7;
    const int m = (int)mbase + p;
    const int pid = groups[m];
    const float* featrow = inputs + ((size_t)(b << 14) + (size_t)pid) * D_;
    const float* f1row = f1 + (size_t)m * D_;
    const float* f2row = f2 + (size_t)m * D_;
    #pragma unroll
    for (int u = 0; u < 12; u++) {
      const int col = seg * 48 + u * 4;
      const float* src = (col < 128) ? featrow + col
                       : (col < 256) ? f1row + (col - 128)
                                     : f2row + (col - 256);
      *(float4*)&x_s[p][col] = *(const float4*)src;
    }
  }

  const int p = t >> 3, es = (t & 7) * 16;
  const int kkb = t >> 4, cb = (t & 15) * 8;
  float4 acc[4] = {{0,0,0,0},{0,0,0,0},{0,0,0,0},{0,0,0,0}};
  for (int k0 = 0; k0 < 384; k0 += 16) {
    const float* wr = W + (size_t)(k0 + kkb) * 128 + cb;
    float4 w0 = *(const float4*)(wr);
    float4 w1 = *(const float4*)(wr + 4);
    __syncthreads();
    *(float4*)&Wc[kkb][cb]     = w0;
    *(float4*)&Wc[kkb][cb + 4] = w1;
    __syncthreads();
    #pragma unroll
    for (int kk = 0; kk < 16; kk++) {
      const float xv = x_s[p][k0 + kk];
      float4 wv0 = *(const float4*)&Wc[kk][es];
      float4 wv1 = *(const float4*)&Wc[kk][es + 4];
      float4 wv2 = *(const float4*)&Wc[kk][es + 8];
      float4 wv3 = *(const float4*)&Wc[kk][es + 12];
      acc[0].x += xv * wv0.x; acc[0].y += xv * wv0.y; acc[0].z += xv * wv0.z; acc[0].w += xv * wv0.w;
      acc[1].x += xv * wv1.x; acc[1].y += xv * wv1.y; acc[1].z += xv * wv1.z; acc[1].w += xv * wv1.w;
      acc[2].x += xv * wv2.x; acc[2].y += xv * wv2.y; acc[2].z += xv * wv2.z; acc[2].w += xv * wv2.w;
      acc[3].x += xv * wv3.x; acc[3].y += xv * wv3.y; acc[3].z += xv * wv3.z; acc[3].w += xv * wv3.w;
    }
  }
  __syncthreads();   // everyone done reading x_s; reuse as h
  float* h_s = &x_s[0][0];   // stride 132
  {
    #pragma unroll
    for (int u = 0; u < 4; u++) {
      float4 bb = *(const float4*)(bias + es + u * 4);
      float4 o;
      o.x = acc[u].x + bb.x; o.y = acc[u].y + bb.y;
      o.z = acc[u].z + bb.z; o.w = acc[u].w + bb.w;
      *(float4*)(h_s + p * 132 + es + u * 4) = o;
    }
  }
  __syncthreads();

  // LayerNorm + ReLU, one row per thread (t < 32)
  if (t < 32) {
    float* row = h_s + t * 132;
    float sum = 0.f, ssq = 0.f;
    #pragma unroll 4
    for (int d = 0; d < 128; d++) { const float v = row[d]; sum += v; ssq += v * v; }
    const float mu = sum * (1.f / 128.f);
    float var = ssq * (1.f / 128.f) - mu * mu;
    const float rstd = rsqrtf(var + 1e-5f);
    #pragma unroll 4
    for (int d = 0; d < 128; d++) {
      const float v = (row[d] - mu) * rstd * ln_g[d] + ln_b[d];
      row[d] = fmaxf(v, 0.f);
    }
  }
  __syncthreads();

  // maxpool over 32 points + grid-reordered out write
  if (t < 128) {
    float mx = h_s[t];
    #pragma unroll
    for (int pp = 1; pp < 32; pp++) mx = fmaxf(mx, h_s[pp * 132 + t]);
    pooled[t] = mx;
    const int mm = g >> 6, nn = (g >> 3) & 7, tt = g & 7;
    const int opos = tt * 64 + nn * 8 + mm;
    out_all[((size_t)b * G_ + opos) * D_ + t] = mx;
  }
  __syncthreads();

  // scatter pooled to every point of the voxel (for_ret)
  {
    const int pid = groups[(int)mbase + p];
    float* dst = out_all + (size_t)BB * G_ * D_
               + ((size_t)(b << 14) + (size_t)pid) * D_ + es;
    #pragma unroll
    for (int u = 0; u < 4; u++)
      *(float4*)(dst + u * 4) = *(const float4*)&pooled[es + u * 4];
  }
}

// ---------------------------------------------------------------------------
extern "C" void kernel_launch(void* const* d_in, const int* in_sizes, int n_in,
                              void* d_out, int out_size, void* d_ws, size_t ws_size,
                              hipStream_t stream) {
  const float* inputs  = (const float*)d_in[0];
  const float* coords  = (const float*)d_in[1];
  const float* qkv_w   = (const float*)d_in[2];   // [2,128,384]
  const float* qkv_b   = (const float*)d_in[3];   // [2,384]
  const float* tbl_x   = (const float*)d_in[4];   // [2,3,50,128]
  const float* tbl_y   = (const float*)d_in[5];
  const float* tbl_z   = (const float*)d_in[6];
  const float* trans_w = (const float*)d_in[7];   // [384,128]
  const float* trans_b = (const float*)d_in[8];
  const float* ln_g    = (const float*)d_in[9];
  const float* ln_b    = (const float*)d_in[10];
  const int*   groups  = (const int*)d_in[11];    // [2,512,32] flat
  // d_in[12] = effective_groups: unused by reference

  float* out = (float*)d_out;
  float* ws  = (float*)d_ws;
  float* qkvbuf = ws;                                  // MT*384 floats
  float* f1 = qkvbuf + (size_t)MT * 384;               // MT*128
  float* f2 = f1 + (size_t)MT * D_;                    // MT*128

  dim3 gg(MT / 64, 3);
  qkv_gemm<<<gg, 256, 0, stream>>>(inputs, groups, qkv_w, qkv_b, qkvbuf);
  attn_kernel<<<BB * G_, 256, 0, stream>>>(qkvbuf, coords, groups,
                                           tbl_x, tbl_y, tbl_z, 0, f1);
  qkv_gemm<<<gg, 256, 0, stream>>>(f1, nullptr, qkv_w + (size_t)D_ * 384,
                                   qkv_b + 384, qkvbuf);
  attn_kernel<<<BB * G_, 256, 0, stream>>>(qkvbuf, coords, groups,
                                           tbl_x, tbl_y, tbl_z, 1, f2);
  trans_kernel<<<BB * G_, 256, 0, stream>>>(inputs, groups, f1, f2,
                                            trans_w, trans_b, ln_g, ln_b, out);
}

// Round 2
// 441.060 us; speedup vs baseline: 2.1672x; 2.1672x over previous
//
#include <hip/hip_runtime.h>
#include <cstddef>

// Voxel encoder: B=2, N=16384, G=512 voxels x K=32 pts, d=128, S=2 layers.
// Pipeline per layer: qkv GEMM -> dk GEMM (bias tables pre-transposed) ->
// per-voxel attention (LDS-only inner loops). Then fused trans GEMM + LN +
// ReLU + maxpool + scatter.
// Bias trick: bias[i,j] = k_i . enc[i,j] = dk[i][ix] + dk[i][50+iy] +
// dk[i][100+iz] with DK = K @ T^T computed as a batched GEMM (round-1's
// in-kernel table gathers were latency-serialized: 5.9% VALUBusy).

#define D_   128
#define VSF  0.25f
#define QSF  0.01f
#define LQ   50
#define G_   512
#define KP   32
#define BB   2
#define NP   16384
#define MT   32768          // B*N rows
#define SCALE 0.08838834764831845f   // 1/sqrt(128)

// ---------------------------------------------------------------------------
// Transpose the (s,1) table slices into Tt[s][k=128][c=256], c = axis*50+l,
// zero-padded for c in [150,256). grid = 256 (s*128+k), block = 256 (c).
// ---------------------------------------------------------------------------
__global__ __launch_bounds__(256) void prep_tt(
    const float* __restrict__ tbl_x, const float* __restrict__ tbl_y,
    const float* __restrict__ tbl_z, float* __restrict__ Tt)
{
  const int c = threadIdx.x;
  const int s = blockIdx.x >> 7;
  const int k = blockIdx.x & 127;
  float v = 0.f;
  if (c < 150) {
    const int axis = c / 50, l = c - axis * 50;
    const float* tb = (axis == 0 ? tbl_x : (axis == 1 ? tbl_y : tbl_z));
    v = tb[(((size_t)s * 3 + 1) * LQ + l) * D_ + k];
  }
  Tt[((size_t)(s * 128 + k)) * 256 + c] = v;
}

// ---------------------------------------------------------------------------
// Generic tiled GEMM, K=128 fixed: C[64 x 128 tile] = A[m,0:128] @ B + bias.
// A row m: optional gather through groups[] (lda applies after gather).
// grid = (M/64, N/128), block = 256.
// ---------------------------------------------------------------------------
__global__ __launch_bounds__(256) void gemm128(
    const float* __restrict__ A, int lda, const int* __restrict__ groups,
    const float* __restrict__ B, int ldb,
    const float* __restrict__ bias,
    float* __restrict__ C, int ldc)
{
  __shared__ __align__(16) float A_s[16][68];   // [k][row], padded
  __shared__ __align__(16) float B_s[16][132];  // [k][col], padded
  const int t  = threadIdx.x;
  const int m0 = blockIdx.x * 64;
  const int n0 = blockIdx.y * 128;

  // A-load mapping: thread -> (row r, k-quad kq)
  const int r  = t >> 2;
  const int kq = (t & 3) * 4;
  const int m  = m0 + r;
  const float* arow;
  if (groups) {
    const int b   = m >> 14;
    const int pid = groups[m];
    arow = A + ((size_t)(b << 14) + (size_t)pid) * lda;
  } else {
    arow = A + (size_t)m * lda;
  }
  // B-load mapping
  const int kkb = t >> 4;
  const int cb  = (t & 15) * 8;
  const float* wbase = B + (size_t)kkb * ldb + n0 + cb;
  // compute mapping: 8 rows x 4 cols per thread
  const int tx = t & 31, ty = t >> 5;

  float acc[8][4];
  #pragma unroll
  for (int i = 0; i < 8; i++)
    #pragma unroll
    for (int j = 0; j < 4; j++) acc[i][j] = 0.f;

  for (int k0 = 0; k0 < 128; k0 += 16) {
    float4 av = *(const float4*)(arow + k0 + kq);
    float4 b0 = *(const float4*)(wbase + (size_t)k0 * ldb);
    float4 b1 = *(const float4*)(wbase + (size_t)k0 * ldb + 4);
    __syncthreads();
    A_s[kq + 0][r] = av.x;
    A_s[kq + 1][r] = av.y;
    A_s[kq + 2][r] = av.z;
    A_s[kq + 3][r] = av.w;
    *(float4*)&B_s[kkb][cb]     = b0;
    *(float4*)&B_s[kkb][cb + 4] = b1;
    __syncthreads();
    #pragma unroll
    for (int kk = 0; kk < 16; kk++) {
      float4 a03 = *(const float4*)&A_s[kk][ty * 8];
      float4 a47 = *(const float4*)&A_s[kk][ty * 8 + 4];
      float4 bv  = *(const float4*)&B_s[kk][tx * 4];
      float a[8] = {a03.x, a03.y, a03.z, a03.w, a47.x, a47.y, a47.z, a47.w};
      float bj[4] = {bv.x, bv.y, bv.z, bv.w};
      #pragma unroll
      for (int i = 0; i < 8; i++)
        #pragma unroll
        for (int j = 0; j < 4; j++)
          acc[i][j] += a[i] * bj[j];
    }
  }
  float4 bsv = {0.f, 0.f, 0.f, 0.f};
  if (bias) bsv = *(const float4*)(bias + n0 + tx * 4);
  #pragma unroll
  for (int i = 0; i < 8; i++) {
    float4 o;
    o.x = acc[i][0] + bsv.x; o.y = acc[i][1] + bsv.y;
    o.z = acc[i][2] + bsv.z; o.w = acc[i][3] + bsv.w;
    *(float4*)(C + (size_t)(m0 + ty * 8 + i) * ldc + n0 + tx * 4) = o;
  }
}

// ---------------------------------------------------------------------------
// Per-voxel attention, dk precomputed. One block per (b,g). All inner loops
// read LDS only. grid = 1024, block = 256.
// ---------------------------------------------------------------------------
__global__ __launch_bounds__(256) void attn2(
    const float* __restrict__ qkv,     // [MT, 384]
    const float* __restrict__ dkb,     // [MT, 256] (cols 0:150 valid)
    const float* __restrict__ coords,  // [B, N, 3]
    const int*   __restrict__ groups,  // [B*N]
    float* __restrict__ fout)          // [MT, 128]
{
  __shared__ __align__(16) float qk_s[32][260];  // q 0:128, k 128:256; later v 0:128
  __shared__ __align__(16) float dk_s[32 * 152];
  __shared__ float sc_s[32 * 33];
  __shared__ float cs[32][3];

  const int t   = threadIdx.x;
  const int bid = blockIdx.x;
  const int b   = bid >> 9;
  const int g   = bid & 511;
  const size_t mbase = (size_t)bid * 32;

  const int p   = t >> 3;        // row 0..31
  const int seg = t & 7;         // 0..7

  // stage q,k: 32 rows x 256 cols (bulk, batched loads)
  {
    const float* src = qkv + (mbase + p) * 384 + seg * 32;
    float* dst = &qk_s[p][seg * 32];
    #pragma unroll
    for (int u = 0; u < 8; u++)
      *(float4*)(dst + u * 4) = *(const float4*)(src + u * 4);
  }
  // stage dk rows (coalesced 32B runs, 19 independent loads/thread)
  {
    const float* dkrow = dkb + (mbase + p) * 256;
    #pragma unroll
    for (int u = 0; u < 19; u++) {
      const int c = u * 8 + seg;
      dk_s[p * 152 + c] = dkrow[c];
    }
  }
  if (t < 32) {
    const int pid = groups[(b << 14) + g * KP + t];
    const float* cp = coords + ((size_t)(b << 14) + (size_t)pid) * 3;
    cs[t][0] = cp[0]; cs[t][1] = cp[1]; cs[t][2] = cp[2];
  }
  __syncthreads();

  // scores: thread (i = p, j in {seg, seg+8, seg+16, seg+24}); q loaded once
  {
    const int i = p;
    const float cix = cs[i][0], ciy = cs[i][1], ciz = cs[i][2];
    const float* qi  = &qk_s[i][0];
    const float* dki = &dk_s[i * 152];
    float4 s4[4] = {{0,0,0,0},{0,0,0,0},{0,0,0,0},{0,0,0,0}};
    #pragma unroll
    for (int d = 0; d < D_; d += 4) {
      float4 qv = *(const float4*)(qi + d);
      #pragma unroll
      for (int jt = 0; jt < 4; jt++) {
        const float4 kv = *(const float4*)(&qk_s[seg + jt * 8][128 + d]);
        s4[jt].x += qv.x * kv.x; s4[jt].y += qv.y * kv.y;
        s4[jt].z += qv.z * kv.z; s4[jt].w += qv.w * kv.w;
      }
    }
    #pragma unroll
    for (int jt = 0; jt < 4; jt++) {
      const int j = seg + jt * 8;
      const float dot = s4[jt].x + s4[jt].y + s4[jt].z + s4[jt].w;
      float dx = cix - cs[j][0], dy = ciy - cs[j][1], dz = ciz - cs[j][2];
      int ix = (int)floorf((dx + VSF) / QSF);
      int iy = (int)floorf((dy + VSF) / QSF);
      int iz = (int)floorf((dz + VSF) / QSF);
      ix = ix < 0 ? 0 : (ix > 49 ? 49 : ix);
      iy = iy < 0 ? 0 : (iy > 49 ? 49 : iy);
      iz = iz < 0 ? 0 : (iz > 49 ? 49 : iz);
      const float biasv = dki[ix] + dki[50 + iy] + dki[100 + iz];
      sc_s[i * 33 + j] = (dot + biasv) * SCALE;
    }
  }
  __syncthreads();

  // softmax (t<32) concurrently with v staging into qk_s[*][0:128]
  {
    const float* src = qkv + (mbase + p) * 384 + 256 + seg * 16;
    float4 v0 = *(const float4*)(src);
    float4 v1 = *(const float4*)(src + 4);
    float4 v2 = *(const float4*)(src + 8);
    float4 v3 = *(const float4*)(src + 12);
    float* dst = &qk_s[p][seg * 16];
    *(float4*)(dst + 0)  = v0;
    *(float4*)(dst + 4)  = v1;
    *(float4*)(dst + 8)  = v2;
    *(float4*)(dst + 12) = v3;
  }
  if (t < 32) {
    float* row = &sc_s[t * 33];
    float mx = row[0];
    #pragma unroll
    for (int j = 1; j < 32; j++) mx = fmaxf(mx, row[j]);
    float sum = 0.f;
    #pragma unroll
    for (int j = 0; j < 32; j++) { float e = __expf(row[j] - mx); row[j] = e; sum += e; }
    const float inv = 1.f / sum;
    #pragma unroll
    for (int j = 0; j < 32; j++) row[j] *= inv;
  }
  __syncthreads();

  // PV from LDS: f[i, es:es+16] = sum_j attn[i,j] * v[j, es:es+16]
  {
    const int i = p, es = seg * 16;
    float4 acc0 = {0,0,0,0}, acc1 = {0,0,0,0}, acc2 = {0,0,0,0}, acc3 = {0,0,0,0};
    #pragma unroll 4
    for (int j = 0; j < 32; j++) {
      const float a = sc_s[i * 33 + j];
      const float* vr = &qk_s[j][es];
      float4 v0 = *(const float4*)(vr);
      float4 v1 = *(const float4*)(vr + 4);
      float4 v2 = *(const float4*)(vr + 8);
      float4 v3 = *(const float4*)(vr + 12);
      acc0.x += a * v0.x; acc0.y += a * v0.y; acc0.z += a * v0.z; acc0.w += a * v0.w;
      acc1.x += a * v1.x; acc1.y += a * v1.y; acc1.z += a * v1.z; acc1.w += a * v1.w;
      acc2.x += a * v2.x; acc2.y += a * v2.y; acc2.z += a * v2.z; acc2.w += a * v2.w;
      acc3.x += a * v3.x; acc3.y += a * v3.y; acc3.z += a * v3.z; acc3.w += a * v3.w;
    }
    float* dst = fout + (mbase + i) * D_ + es;
    *(float4*)(dst + 0)  = acc0;
    *(float4*)(dst + 4)  = acc1;
    *(float4*)(dst + 8)  = acc2;
    *(float4*)(dst + 12) = acc3;
  }
}

// ---------------------------------------------------------------------------
// Fused epilogue: x=[feats|f1|f2] (staged), h = x@W + b, LayerNorm, ReLU,
// maxpool over 32 points, write grid-reordered `out` + per-point scatter.
// One block per (b,g). grid = 1024, block = 256.
// ---------------------------------------------------------------------------
__global__ __launch_bounds__(256) void trans_kernel(
    const float* __restrict__ inputs, const int* __restrict__ groups,
    const float* __restrict__ f1, const float* __restrict__ f2,
    const float* __restrict__ W,      // [384,128]
    const float* __restrict__ bias,   // [128]
    const float* __restrict__ ln_g, const float* __restrict__ ln_b,
    float* __restrict__ out_all)
{
  __shared__ __align__(16) float x_s[32][388];   // reused as h[32][132] later
  __shared__ __align__(16) float Wc[16][132];
  __shared__ float pooled[128];

  const int t   = threadIdx.x;
  const int bid = blockIdx.x;
  const int b   = bid >> 9;
  const int g   = bid & 511;
  const size_t mbase = (size_t)bid * 32;

  // stage x = [feats(gathered) | f1 | f2]
  {
    const int p = t >> 3, seg = t & 7;
    const int m = (int)mbase + p;
    const int pid = groups[m];
    const float* featrow = inputs + ((size_t)(b << 14) + (size_t)pid) * D_;
    const float* f1row = f1 + (size_t)m * D_;
    const float* f2row = f2 + (size_t)m * D_;
    #pragma unroll
    for (int u = 0; u < 12; u++) {
      const int col = seg * 48 + u * 4;
      const float* src = (col < 128) ? featrow + col
                       : (col < 256) ? f1row + (col - 128)
                                     : f2row + (col - 256);
      *(float4*)&x_s[p][col] = *(const float4*)src;
    }
  }

  const int p = t >> 3, es = (t & 7) * 16;
  const int kkb = t >> 4, cb = (t & 15) * 8;
  float4 acc[4] = {{0,0,0,0},{0,0,0,0},{0,0,0,0},{0,0,0,0}};
  for (int k0 = 0; k0 < 384; k0 += 16) {
    const float* wr = W + (size_t)(k0 + kkb) * 128 + cb;
    float4 w0 = *(const float4*)(wr);
    float4 w1 = *(const float4*)(wr + 4);
    __syncthreads();
    *(float4*)&Wc[kkb][cb]     = w0;
    *(float4*)&Wc[kkb][cb + 4] = w1;
    __syncthreads();
    #pragma unroll
    for (int kk = 0; kk < 16; kk++) {
      const float xv = x_s[p][k0 + kk];
      float4 wv0 = *(const float4*)&Wc[kk][es];
      float4 wv1 = *(const float4*)&Wc[kk][es + 4];
      float4 wv2 = *(const float4*)&Wc[kk][es + 8];
      float4 wv3 = *(const float4*)&Wc[kk][es + 12];
      acc[0].x += xv * wv0.x; acc[0].y += xv * wv0.y; acc[0].z += xv * wv0.z; acc[0].w += xv * wv0.w;
      acc[1].x += xv * wv1.x; acc[1].y += xv * wv1.y; acc[1].z += xv * wv1.z; acc[1].w += xv * wv1.w;
      acc[2].x += xv * wv2.x; acc[2].y += xv * wv2.y; acc[2].z += xv * wv2.z; acc[2].w += xv * wv2.w;
      acc[3].x += xv * wv3.x; acc[3].y += xv * wv3.y; acc[3].z += xv * wv3.z; acc[3].w += xv * wv3.w;
    }
  }
  __syncthreads();   // everyone done reading x_s; reuse as h
  float* h_s = &x_s[0][0];   // stride 132
  {
    #pragma unroll
    for (int u = 0; u < 4; u++) {
      float4 bb = *(const float4*)(bias + es + u * 4);
      float4 o;
      o.x = acc[u].x + bb.x; o.y = acc[u].y + bb.y;
      o.z = acc[u].z + bb.z; o.w = acc[u].w + bb.w;
      *(float4*)(h_s + p * 132 + es + u * 4) = o;
    }
  }
  __syncthreads();

  // LayerNorm + ReLU, one row per thread (t < 32)
  if (t < 32) {
    float* row = h_s + t * 132;
    float sum = 0.f, ssq = 0.f;
    #pragma unroll 4
    for (int d = 0; d < 128; d++) { const float v = row[d]; sum += v; ssq += v * v; }
    const float mu = sum * (1.f / 128.f);
    float var = ssq * (1.f / 128.f) - mu * mu;
    const float rstd = rsqrtf(var + 1e-5f);
    #pragma unroll 4
    for (int d = 0; d < 128; d++) {
      const float v = (row[d] - mu) * rstd * ln_g[d] + ln_b[d];
      row[d] = fmaxf(v, 0.f);
    }
  }
  __syncthreads();

  // maxpool over 32 points + grid-reordered out write
  if (t < 128) {
    float mx = h_s[t];
    #pragma unroll
    for (int pp = 1; pp < 32; pp++) mx = fmaxf(mx, h_s[pp * 132 + t]);
    pooled[t] = mx;
    const int mm = g >> 6, nn = (g >> 3) & 7, tt = g & 7;
    const int opos = tt * 64 + nn * 8 + mm;
    out_all[((size_t)b * G_ + opos) * D_ + t] = mx;
  }
  __syncthreads();

  // scatter pooled to every point of the voxel (for_ret)
  {
    const int pid = groups[(int)mbase + p];
    float* dst = out_all + (size_t)BB * G_ * D_
               + ((size_t)(b << 14) + (size_t)pid) * D_ + es;
    #pragma unroll
    for (int u = 0; u < 4; u++)
      *(float4*)(dst + u * 4) = *(const float4*)&pooled[es + u * 4];
  }
}

// ---------------------------------------------------------------------------
extern "C" void kernel_launch(void* const* d_in, const int* in_sizes, int n_in,
                              void* d_out, int out_size, void* d_ws, size_t ws_size,
                              hipStream_t stream) {
  const float* inputs  = (const float*)d_in[0];
  const float* coords  = (const float*)d_in[1];
  const float* qkv_w   = (const float*)d_in[2];   // [2,128,384]
  const float* qkv_b   = (const float*)d_in[3];   // [2,384]
  const float* tbl_x   = (const float*)d_in[4];   // [2,3,50,128]
  const float* tbl_y   = (const float*)d_in[5];
  const float* tbl_z   = (const float*)d_in[6];
  const float* trans_w = (const float*)d_in[7];   // [384,128]
  const float* trans_b = (const float*)d_in[8];
  const float* ln_g    = (const float*)d_in[9];
  const float* ln_b    = (const float*)d_in[10];
  const int*   groups  = (const int*)d_in[11];    // [2,512,32] flat
  // d_in[12] = effective_groups: unused by reference

  float* out = (float*)d_out;
  float* ws  = (float*)d_ws;
  float* qkvbuf = ws;                                  // MT*384
  float* f1  = qkvbuf + (size_t)MT * 384;              // MT*128
  float* f2  = f1 + (size_t)MT * D_;                   // MT*128
  float* dkb = f2 + (size_t)MT * D_;                   // MT*256
  float* Tt  = dkb + (size_t)MT * 256;                 // 2*128*256

  prep_tt<<<256, 256, 0, stream>>>(tbl_x, tbl_y, tbl_z, Tt);

  dim3 gq(MT / 64, 3);
  dim3 gd(MT / 64, 2);
  // layer 0
  gemm128<<<gq, 256, 0, stream>>>(inputs, D_, groups, qkv_w, 384, qkv_b,
                                  qkvbuf, 384);
  gemm128<<<gd, 256, 0, stream>>>(qkvbuf + 128, 384, nullptr, Tt, 256, nullptr,
                                  dkb, 256);
  attn2<<<BB * G_, 256, 0, stream>>>(qkvbuf, dkb, coords, groups, f1);
  // layer 1
  gemm128<<<gq, 256, 0, stream>>>(f1, D_, nullptr, qkv_w + (size_t)D_ * 384,
                                  384, qkv_b + 384, qkvbuf, 384);
  gemm128<<<gd, 256, 0, stream>>>(qkvbuf + 128, 384, nullptr,
                                  Tt + (size_t)128 * 256, 256, nullptr,
                                  dkb, 256);
  attn2<<<BB * G_, 256, 0, stream>>>(qkvbuf, dkb, coords, groups, f2);
  // epilogue
  trans_kernel<<<BB * G_, 256, 0, stream>>>(inputs, groups, f1, f2,
                                            trans_w, trans_b, ln_g, ln_b, out);
}

// Round 3
// 365.305 us; speedup vs baseline: 2.6166x; 1.2074x over previous
//
#include <hip/hip_runtime.h>
#include <cstddef>

// Voxel encoder: B=2, N=16384, G=512 voxels x K=32 pts, d=128, S=2 layers.
// Per layer: fused qkv+dk GEMM (dk folded: dk = F@(Wk@T^T) + bk@T^T) ->
// per-voxel attention (LDS-only inner loops). Epilogue: trans GEMM (K=384)
// with fused bias+LayerNorm(shuffle)+ReLU+maxpool+scatter.

#define D_   128
#define VSF  0.25f
#define QSF  0.01f
#define LQ   50
#define G_   512
#define KP   32
#define BB   2
#define NP   16384
#define MT   32768          // B*N rows
#define SCALE 0.08838834764831845f   // 1/sqrt(128)

// ---------------------------------------------------------------------------
// Transpose the (s,1) table slices into Tt[s][e=128][c=256], c = axis*50+l,
// zero-padded for c in [150,256). grid = 256 (s*128+e), block = 256 (c).
// ---------------------------------------------------------------------------
__global__ __launch_bounds__(256) void prep_tt(
    const float* __restrict__ tbl_x, const float* __restrict__ tbl_y,
    const float* __restrict__ tbl_z, float* __restrict__ Tt)
{
  const int c = threadIdx.x;
  const int s = blockIdx.x >> 7;
  const int e = blockIdx.x & 127;
  float v = 0.f;
  if (c < 150) {
    const int axis = c / 50, l = c - axis * 50;
    const float* tb = (axis == 0 ? tbl_x : (axis == 1 ? tbl_y : tbl_z));
    v = tb[(((size_t)s * 3 + 1) * LQ + l) * D_ + e];
  }
  Tt[((size_t)(s * 128 + e)) * 256 + c] = v;
}

// bf[s][c] = sum_e qkv_b[s][128+e] * Tt[s][e][c].  grid=2, block=256.
__global__ __launch_bounds__(256) void prep_bf(
    const float* __restrict__ qkv_b, const float* __restrict__ Tt,
    float* __restrict__ bf)
{
  const int s = blockIdx.x, c = threadIdx.x;
  const float* bk = qkv_b + (size_t)s * 384 + 128;
  const float* T  = Tt + (size_t)s * 128 * 256 + c;
  float acc = 0.f;
  #pragma unroll 4
  for (int e = 0; e < 128; e++) acc += bk[e] * T[(size_t)e * 256];
  bf[s * 256 + c] = acc;
}

// ---------------------------------------------------------------------------
// Generic tiled GEMM, K=128: C[64x128 tile] = A @ B + bias (optional gather).
// grid = (M/64, N/128), block = 256.
// ---------------------------------------------------------------------------
__global__ __launch_bounds__(256) void gemm128(
    const float* __restrict__ A, int lda, const int* __restrict__ groups,
    const float* __restrict__ B, int ldb,
    const float* __restrict__ bias,
    float* __restrict__ C, int ldc)
{
  __shared__ __align__(16) float A_s[16][68];
  __shared__ __align__(16) float B_s[16][132];
  const int t  = threadIdx.x;
  const int m0 = blockIdx.x * 64;
  const int n0 = blockIdx.y * 128;

  const int r  = t >> 2;
  const int kq = (t & 3) * 4;
  const int m  = m0 + r;
  const float* arow;
  if (groups) {
    const int b   = m >> 14;
    const int pid = groups[m];
    arow = A + ((size_t)(b << 14) + (size_t)pid) * lda;
  } else {
    arow = A + (size_t)m * lda;
  }
  const int kkb = t >> 4;
  const int cb  = (t & 15) * 8;
  const float* wbase = B + (size_t)kkb * ldb + n0 + cb;
  const int tx = t & 31, ty = t >> 5;

  float acc[8][4];
  #pragma unroll
  for (int i = 0; i < 8; i++)
    #pragma unroll
    for (int j = 0; j < 4; j++) acc[i][j] = 0.f;

  for (int k0 = 0; k0 < 128; k0 += 16) {
    float4 av = *(const float4*)(arow + k0 + kq);
    float4 b0 = *(const float4*)(wbase + (size_t)k0 * ldb);
    float4 b1 = *(const float4*)(wbase + (size_t)k0 * ldb + 4);
    __syncthreads();
    A_s[kq + 0][r] = av.x;
    A_s[kq + 1][r] = av.y;
    A_s[kq + 2][r] = av.z;
    A_s[kq + 3][r] = av.w;
    *(float4*)&B_s[kkb][cb]     = b0;
    *(float4*)&B_s[kkb][cb + 4] = b1;
    __syncthreads();
    #pragma unroll
    for (int kk = 0; kk < 16; kk++) {
      float4 a03 = *(const float4*)&A_s[kk][ty * 8];
      float4 a47 = *(const float4*)&A_s[kk][ty * 8 + 4];
      float4 bv  = *(const float4*)&B_s[kk][tx * 4];
      float a[8] = {a03.x, a03.y, a03.z, a03.w, a47.x, a47.y, a47.z, a47.w};
      float bj[4] = {bv.x, bv.y, bv.z, bv.w};
      #pragma unroll
      for (int i = 0; i < 8; i++)
        #pragma unroll
        for (int j = 0; j < 4; j++)
          acc[i][j] += a[i] * bj[j];
    }
  }
  float4 bsv = {0.f, 0.f, 0.f, 0.f};
  if (bias) bsv = *(const float4*)(bias + n0 + tx * 4);
  #pragma unroll
  for (int i = 0; i < 8; i++) {
    float4 o;
    o.x = acc[i][0] + bsv.x; o.y = acc[i][1] + bsv.y;
    o.z = acc[i][2] + bsv.z; o.w = acc[i][3] + bsv.w;
    *(float4*)(C + (size_t)(m0 + ty * 8 + i) * ldc + n0 + tx * 4) = o;
  }
}

// ---------------------------------------------------------------------------
// Fused qkv + dk GEMM (K=128). grid=(512,5): y<3 -> qkv tile, y>=3 -> dk.
// ---------------------------------------------------------------------------
__global__ __launch_bounds__(256) void qkv_dk_gemm(
    const float* __restrict__ A, int lda, const int* __restrict__ groups,
    const float* __restrict__ Wqkv, const float* __restrict__ bqkv,
    const float* __restrict__ Wf,   const float* __restrict__ bf,
    float* __restrict__ Cqkv, float* __restrict__ Cdk)
{
  __shared__ __align__(16) float A_s[16][68];
  __shared__ __align__(16) float B_s[16][132];
  const int t  = threadIdx.x;
  const int m0 = blockIdx.x * 64;
  const int y  = blockIdx.y;
  const bool is_dk = (y >= 3);
  const int n0  = is_dk ? (y - 3) * 128 : y * 128;
  const int ldb = is_dk ? 256 : 384;
  const int ldc = ldb;
  const float* B    = is_dk ? Wf : Wqkv;
  const float* bias = is_dk ? bf : bqkv;
  float* C          = is_dk ? Cdk : Cqkv;

  const int r  = t >> 2;
  const int kq = (t & 3) * 4;
  const int m  = m0 + r;
  const float* arow;
  if (groups) {
    const int b   = m >> 14;
    const int pid = groups[m];
    arow = A + ((size_t)(b << 14) + (size_t)pid) * lda;
  } else {
    arow = A + (size_t)m * lda;
  }
  const int kkb = t >> 4;
  const int cb  = (t & 15) * 8;
  const float* wbase = B + (size_t)kkb * ldb + n0 + cb;
  const int tx = t & 31, ty = t >> 5;

  float acc[8][4];
  #pragma unroll
  for (int i = 0; i < 8; i++)
    #pragma unroll
    for (int j = 0; j < 4; j++) acc[i][j] = 0.f;

  for (int k0 = 0; k0 < 128; k0 += 16) {
    float4 av = *(const float4*)(arow + k0 + kq);
    float4 b0 = *(const float4*)(wbase + (size_t)k0 * ldb);
    float4 b1 = *(const float4*)(wbase + (size_t)k0 * ldb + 4);
    __syncthreads();
    A_s[kq + 0][r] = av.x;
    A_s[kq + 1][r] = av.y;
    A_s[kq + 2][r] = av.z;
    A_s[kq + 3][r] = av.w;
    *(float4*)&B_s[kkb][cb]     = b0;
    *(float4*)&B_s[kkb][cb + 4] = b1;
    __syncthreads();
    #pragma unroll
    for (int kk = 0; kk < 16; kk++) {
      float4 a03 = *(const float4*)&A_s[kk][ty * 8];
      float4 a47 = *(const float4*)&A_s[kk][ty * 8 + 4];
      float4 bv  = *(const float4*)&B_s[kk][tx * 4];
      float a[8] = {a03.x, a03.y, a03.z, a03.w, a47.x, a47.y, a47.z, a47.w};
      float bj[4] = {bv.x, bv.y, bv.z, bv.w};
      #pragma unroll
      for (int i = 0; i < 8; i++)
        #pragma unroll
        for (int j = 0; j < 4; j++)
          acc[i][j] += a[i] * bj[j];
    }
  }
  float4 bsv = *(const float4*)(bias + n0 + tx * 4);
  #pragma unroll
  for (int i = 0; i < 8; i++) {
    float4 o;
    o.x = acc[i][0] + bsv.x; o.y = acc[i][1] + bsv.y;
    o.z = acc[i][2] + bsv.z; o.w = acc[i][3] + bsv.w;
    *(float4*)(C + (size_t)(m0 + ty * 8 + i) * ldc + n0 + tx * 4) = o;
  }
}

// ---------------------------------------------------------------------------
// Per-voxel attention, dk precomputed. One block per (b,g). grid=1024.
// ---------------------------------------------------------------------------
__global__ __launch_bounds__(256) void attn2(
    const float* __restrict__ qkv,     // [MT, 384]
    const float* __restrict__ dkb,     // [MT, 256] (cols 0:150 valid)
    const float* __restrict__ coords,  // [B, N, 3]
    const int*   __restrict__ groups,  // [B*N]
    float* __restrict__ fout)          // [MT, 128]
{
  __shared__ __align__(16) float qk_s[32][260];  // q 0:128, k 128:256; later v 0:128
  __shared__ __align__(16) float dk_s[32 * 152];
  __shared__ float sc_s[32 * 33];
  __shared__ float cs[32][3];

  const int t   = threadIdx.x;
  const int bid = blockIdx.x;
  const int b   = bid >> 9;
  const int g   = bid & 511;
  const size_t mbase = (size_t)bid * 32;

  const int p   = t >> 3;
  const int seg = t & 7;

  {
    const float* src = qkv + (mbase + p) * 384 + seg * 32;
    float* dst = &qk_s[p][seg * 32];
    #pragma unroll
    for (int u = 0; u < 8; u++)
      *(float4*)(dst + u * 4) = *(const float4*)(src + u * 4);
  }
  {
    const float* dkrow = dkb + (mbase + p) * 256;
    #pragma unroll
    for (int u = 0; u < 19; u++) {
      const int c = u * 8 + seg;
      dk_s[p * 152 + c] = dkrow[c];
    }
  }
  if (t < 32) {
    const int pid = groups[(b << 14) + g * KP + t];
    const float* cp = coords + ((size_t)(b << 14) + (size_t)pid) * 3;
    cs[t][0] = cp[0]; cs[t][1] = cp[1]; cs[t][2] = cp[2];
  }
  __syncthreads();

  {
    const int i = p;
    const float cix = cs[i][0], ciy = cs[i][1], ciz = cs[i][2];
    const float* qi  = &qk_s[i][0];
    const float* dki = &dk_s[i * 152];
    float4 s4[4] = {{0,0,0,0},{0,0,0,0},{0,0,0,0},{0,0,0,0}};
    #pragma unroll
    for (int d = 0; d < D_; d += 4) {
      float4 qv = *(const float4*)(qi + d);
      #pragma unroll
      for (int jt = 0; jt < 4; jt++) {
        const float4 kv = *(const float4*)(&qk_s[seg + jt * 8][128 + d]);
        s4[jt].x += qv.x * kv.x; s4[jt].y += qv.y * kv.y;
        s4[jt].z += qv.z * kv.z; s4[jt].w += qv.w * kv.w;
      }
    }
    #pragma unroll
    for (int jt = 0; jt < 4; jt++) {
      const int j = seg + jt * 8;
      const float dot = s4[jt].x + s4[jt].y + s4[jt].z + s4[jt].w;
      float dx = cix - cs[j][0], dy = ciy - cs[j][1], dz = ciz - cs[j][2];
      int ix = (int)floorf((dx + VSF) / QSF);
      int iy = (int)floorf((dy + VSF) / QSF);
      int iz = (int)floorf((dz + VSF) / QSF);
      ix = ix < 0 ? 0 : (ix > 49 ? 49 : ix);
      iy = iy < 0 ? 0 : (iy > 49 ? 49 : iy);
      iz = iz < 0 ? 0 : (iz > 49 ? 49 : iz);
      const float biasv = dki[ix] + dki[50 + iy] + dki[100 + iz];
      sc_s[i * 33 + j] = (dot + biasv) * SCALE;
    }
  }
  __syncthreads();

  {
    const float* src = qkv + (mbase + p) * 384 + 256 + seg * 16;
    float4 v0 = *(const float4*)(src);
    float4 v1 = *(const float4*)(src + 4);
    float4 v2 = *(const float4*)(src + 8);
    float4 v3 = *(const float4*)(src + 12);
    float* dst = &qk_s[p][seg * 16];
    *(float4*)(dst + 0)  = v0;
    *(float4*)(dst + 4)  = v1;
    *(float4*)(dst + 8)  = v2;
    *(float4*)(dst + 12) = v3;
  }
  if (t < 32) {
    float* row = &sc_s[t * 33];
    float mx = row[0];
    #pragma unroll
    for (int j = 1; j < 32; j++) mx = fmaxf(mx, row[j]);
    float sum = 0.f;
    #pragma unroll
    for (int j = 0; j < 32; j++) { float e = __expf(row[j] - mx); row[j] = e; sum += e; }
    const float inv = 1.f / sum;
    #pragma unroll
    for (int j = 0; j < 32; j++) row[j] *= inv;
  }
  __syncthreads();

  {
    const int i = p, es = seg * 16;
    float4 acc0 = {0,0,0,0}, acc1 = {0,0,0,0}, acc2 = {0,0,0,0}, acc3 = {0,0,0,0};
    #pragma unroll 4
    for (int j = 0; j < 32; j++) {
      const float a = sc_s[i * 33 + j];
      const float* vr = &qk_s[j][es];
      float4 v0 = *(const float4*)(vr);
      float4 v1 = *(const float4*)(vr + 4);
      float4 v2 = *(const float4*)(vr + 8);
      float4 v3 = *(const float4*)(vr + 12);
      acc0.x += a * v0.x; acc0.y += a * v0.y; acc0.z += a * v0.z; acc0.w += a * v0.w;
      acc1.x += a * v1.x; acc1.y += a * v1.y; acc1.z += a * v1.z; acc1.w += a * v1.w;
      acc2.x += a * v2.x; acc2.y += a * v2.y; acc2.z += a * v2.z; acc2.w += a * v2.w;
      acc3.x += a * v3.x; acc3.y += a * v3.y; acc3.z += a * v3.z; acc3.w += a * v3.w;
    }
    float* dst = fout + (mbase + i) * D_ + es;
    *(float4*)(dst + 0)  = acc0;
    *(float4*)(dst + 4)  = acc1;
    *(float4*)(dst + 8)  = acc2;
    *(float4*)(dst + 12) = acc3;
  }
}

// ---------------------------------------------------------------------------
// Trans GEMM K=384 with fused epilogue. 64 rows (=2 voxels) per block.
// h = [feats|f1|f2] @ W + b; LN via 32-lane shuffle; ReLU; maxpool in LDS;
// grid-reordered out write + per-point scatter. grid=512, block=256.
// ---------------------------------------------------------------------------
__global__ __launch_bounds__(256) void trans_fused(
    const float* __restrict__ inputs, const int* __restrict__ groups,
    const float* __restrict__ f1, const float* __restrict__ f2,
    const float* __restrict__ W,      // [384,128]
    const float* __restrict__ bias,   // [128]
    const float* __restrict__ ln_g, const float* __restrict__ ln_b,
    float* __restrict__ out_all)
{
  __shared__ __align__(16) float A_s[16][68];
  __shared__ __align__(16) float B_s[16][132];
  __shared__ __align__(16) float h_s[64][132];
  __shared__ float pooled_s[2][128];

  const int t  = threadIdx.x;
  const int m0 = blockIdx.x * 64;
  const int bb = m0 >> 14;          // batch (uniform per block)

  // A sources for row r
  const int r  = t >> 2;
  const int kq = (t & 3) * 4;
  const int m  = m0 + r;
  const int pid = groups[m];
  const float* featrow = inputs + ((size_t)(bb << 14) + (size_t)pid) * D_;
  const float* f1row   = f1 + (size_t)m * D_;
  const float* f2row   = f2 + (size_t)m * D_;

  const int kkb = t >> 4;
  const int cb  = (t & 15) * 8;
  const int tx  = t & 31, ty = t >> 5;

  float acc[8][4];
  #pragma unroll
  for (int i = 0; i < 8; i++)
    #pragma unroll
    for (int j = 0; j < 4; j++) acc[i][j] = 0.f;

  for (int k0 = 0; k0 < 384; k0 += 16) {
    const float* asrc = (k0 < 128) ? featrow + k0 + kq
                      : (k0 < 256) ? f1row + (k0 - 128) + kq
                                   : f2row + (k0 - 256) + kq;
    float4 av = *(const float4*)asrc;
    const float* wr = W + (size_t)(k0 + kkb) * 128 + cb;
    float4 b0 = *(const float4*)(wr);
    float4 b1 = *(const float4*)(wr + 4);
    __syncthreads();
    A_s[kq + 0][r] = av.x;
    A_s[kq + 1][r] = av.y;
    A_s[kq + 2][r] = av.z;
    A_s[kq + 3][r] = av.w;
    *(float4*)&B_s[kkb][cb]     = b0;
    *(float4*)&B_s[kkb][cb + 4] = b1;
    __syncthreads();
    #pragma unroll
    for (int kk = 0; kk < 16; kk++) {
      float4 a03 = *(const float4*)&A_s[kk][ty * 8];
      float4 a47 = *(const float4*)&A_s[kk][ty * 8 + 4];
      float4 bv  = *(const float4*)&B_s[kk][tx * 4];
      float a[8] = {a03.x, a03.y, a03.z, a03.w, a47.x, a47.y, a47.z, a47.w};
      float bj[4] = {bv.x, bv.y, bv.z, bv.w};
      #pragma unroll
      for (int i = 0; i < 8; i++)
        #pragma unroll
        for (int j = 0; j < 4; j++)
          acc[i][j] += a[i] * bj[j];
    }
  }

  // fused bias + LayerNorm (row lives on the 32 tx-lanes of this ty) + ReLU
  const float4 bsv = *(const float4*)(bias + tx * 4);
  const float4 lgv = *(const float4*)(ln_g + tx * 4);
  const float4 lbv = *(const float4*)(ln_b + tx * 4);
  __syncthreads();   // done reading A_s/B_s (h_s separate, but order anyway)
  #pragma unroll
  for (int i = 0; i < 8; i++) {
    float h0 = acc[i][0] + bsv.x;
    float h1 = acc[i][1] + bsv.y;
    float h2 = acc[i][2] + bsv.z;
    float h3 = acc[i][3] + bsv.w;
    float s  = h0 + h1 + h2 + h3;
    float ss = h0 * h0 + h1 * h1 + h2 * h2 + h3 * h3;
    #pragma unroll
    for (int mk = 16; mk >= 1; mk >>= 1) {
      s  += __shfl_xor(s, mk);
      ss += __shfl_xor(ss, mk);
    }
    const float mu   = s * (1.f / 128.f);
    const float var  = ss * (1.f / 128.f) - mu * mu;
    const float rstd = rsqrtf(var + 1e-5f);
    float4 o;
    o.x = fmaxf((h0 - mu) * rstd * lgv.x + lbv.x, 0.f);
    o.y = fmaxf((h1 - mu) * rstd * lgv.y + lbv.y, 0.f);
    o.z = fmaxf((h2 - mu) * rstd * lgv.z + lbv.z, 0.f);
    o.w = fmaxf((h3 - mu) * rstd * lgv.w + lbv.w, 0.f);
    *(float4*)&h_s[ty * 8 + i][tx * 4] = o;
  }
  __syncthreads();

  // maxpool over the 32 rows of each of the 2 voxels
  {
    const int v = t >> 7, c = t & 127;
    float mx = h_s[v * 32][c];
    #pragma unroll 4
    for (int rr = 1; rr < 32; rr++) mx = fmaxf(mx, h_s[v * 32 + rr][c]);
    pooled_s[v][c] = mx;
    const int gv = blockIdx.x * 2 + v;
    const int bo = gv >> 9, g = gv & 511;
    const int mm = g >> 6, nn = (g >> 3) & 7, tt = g & 7;
    const int opos = tt * 64 + nn * 8 + mm;
    out_all[((size_t)bo * G_ + opos) * D_ + c] = mx;
  }
  __syncthreads();

  // scatter pooled to every point (for_ret). row r = t>>2, 32-col segment.
  {
    const int qs = (t & 3) * 32;
    const int v  = r >> 5;
    float* dst = out_all + (size_t)BB * G_ * D_
               + ((size_t)(bb << 14) + (size_t)pid) * D_ + qs;
    const float* src = &pooled_s[v][qs];
    #pragma unroll
    for (int u = 0; u < 8; u++)
      *(float4*)(dst + u * 4) = *(const float4*)(src + u * 4);
  }
}

// ---------------------------------------------------------------------------
extern "C" void kernel_launch(void* const* d_in, const int* in_sizes, int n_in,
                              void* d_out, int out_size, void* d_ws, size_t ws_size,
                              hipStream_t stream) {
  const float* inputs  = (const float*)d_in[0];
  const float* coords  = (const float*)d_in[1];
  const float* qkv_w   = (const float*)d_in[2];   // [2,128,384]
  const float* qkv_b   = (const float*)d_in[3];   // [2,384]
  const float* tbl_x   = (const float*)d_in[4];   // [2,3,50,128]
  const float* tbl_y   = (const float*)d_in[5];
  const float* tbl_z   = (const float*)d_in[6];
  const float* trans_w = (const float*)d_in[7];   // [384,128]
  const float* trans_b = (const float*)d_in[8];
  const float* ln_g    = (const float*)d_in[9];
  const float* ln_b    = (const float*)d_in[10];
  const int*   groups  = (const int*)d_in[11];    // [2,512,32] flat

  float* out = (float*)d_out;
  float* ws  = (float*)d_ws;
  float* qkvbuf = ws;                                  // MT*384
  float* f1  = qkvbuf + (size_t)MT * 384;              // MT*128
  float* f2  = f1 + (size_t)MT * D_;                   // MT*128
  float* dkb = f2 + (size_t)MT * D_;                   // MT*256
  float* Tt  = dkb + (size_t)MT * 256;                 // 2*128*256
  float* Wf  = Tt + (size_t)2 * 128 * 256;             // 2*128*256
  float* bf  = Wf + (size_t)2 * 128 * 256;             // 2*256

  // prep: Tt, Wf = Wk@Tt, bf = bk@Tt
  prep_tt<<<256, 256, 0, stream>>>(tbl_x, tbl_y, tbl_z, Tt);
  for (int s = 0; s < 2; s++) {
    gemm128<<<dim3(2, 2), 256, 0, stream>>>(
        qkv_w + (size_t)s * 128 * 384 + 128, 384, nullptr,
        Tt + (size_t)s * 128 * 256, 256, nullptr,
        Wf + (size_t)s * 128 * 256, 256);
  }
  prep_bf<<<2, 256, 0, stream>>>(qkv_b, Tt, bf);

  // layer 0
  qkv_dk_gemm<<<dim3(MT / 64, 5), 256, 0, stream>>>(
      inputs, D_, groups, qkv_w, qkv_b, Wf, bf, qkvbuf, dkb);
  attn2<<<BB * G_, 256, 0, stream>>>(qkvbuf, dkb, coords, groups, f1);
  // layer 1
  qkv_dk_gemm<<<dim3(MT / 64, 5), 256, 0, stream>>>(
      f1, D_, nullptr, qkv_w + (size_t)D_ * 384, qkv_b + 384,
      Wf + (size_t)128 * 256, bf + 256, qkvbuf, dkb);
  attn2<<<BB * G_, 256, 0, stream>>>(qkvbuf, dkb, coords, groups, f2);
  // epilogue
  trans_fused<<<MT / 64, 256, 0, stream>>>(inputs, groups, f1, f2,
                                           trans_w, trans_b, ln_g, ln_b, out);
}

// Round 4
// 257.015 us; speedup vs baseline: 3.7190x; 1.4213x over previous
//
#include <hip/hip_runtime.h>
#include <cstddef>

// Voxel encoder: B=2, N=16384, G=512 voxels x K=32 pts, d=128, S=2 layers.
// Round 4: all GEMMs moved to bf16 MFMA (16x16x32, fp32 accum), LDS-free:
//   A frags (A[m=lane&15][k=quad*8+j]) load straight from row-major bf16
//   activations (gather folds into the row pointer); B (weights) pre-packed
//   into fragment-major layout at prep time (one dwordx4 per lane per frag).
// attn2 unchanged (fp32, LDS) but emits f1/f2 as bf16 for downstream GEMMs.
// trans keeps fused shuffle-LN/ReLU/maxpool/scatter epilogue on C-fragments.

#define D_   128
#define VSF  0.25f
#define QSF  0.01f
#define LQ   50
#define G_   512
#define KP   32
#define BB   2
#define NP   16384
#define MT   32768          // B*N rows
#define SCALE 0.08838834764831845f   // 1/sqrt(128)

using short8 = __attribute__((ext_vector_type(8))) short;
using f32x4  = __attribute__((ext_vector_type(4))) float;

__device__ inline unsigned short f2bf(float x) {
  unsigned u = __builtin_bit_cast(unsigned, x);
  u += 0x7fffu + ((u >> 16) & 1u);      // round-to-nearest-even
  return (unsigned short)(u >> 16);
}
__device__ inline short8 as_short8(uint4 v) {
  union { uint4 u; short8 s; } x; x.u = v; return x.s;
}

// ---------------------------------------------------------------------------
// fp32 -> bf16 bulk convert (8 elems/thread). grid = n/(256*8).
// ---------------------------------------------------------------------------
__global__ __launch_bounds__(256) void cvt_bf16(
    const float* __restrict__ in, unsigned short* __restrict__ outp)
{
  const size_t i = ((size_t)blockIdx.x * 256 + threadIdx.x) * 8;
  float4 a = *(const float4*)(in + i);
  float4 b = *(const float4*)(in + i + 4);
  uint4 o;
  o.x = f2bf(a.x) | ((unsigned)f2bf(a.y) << 16);
  o.y = f2bf(a.z) | ((unsigned)f2bf(a.w) << 16);
  o.z = f2bf(b.x) | ((unsigned)f2bf(b.y) << 16);
  o.w = f2bf(b.z) | ((unsigned)f2bf(b.w) << 16);
  *(uint4*)(outp + i) = o;
}

// ---------------------------------------------------------------------------
// Transpose the (s,1) table slices into Tt[s][e=128][c=256], c = axis*50+l,
// zero-padded for c in [150,256). grid = 256 (s*128+e), block = 256 (c).
// ---------------------------------------------------------------------------
__global__ __launch_bounds__(256) void prep_tt(
    const float* __restrict__ tbl_x, const float* __restrict__ tbl_y,
    const float* __restrict__ tbl_z, float* __restrict__ Tt)
{
  const int c = threadIdx.x;
  const int s = blockIdx.x >> 7;
  const int e = blockIdx.x & 127;
  float v = 0.f;
  if (c < 150) {
    const int axis = c / 50, l = c - axis * 50;
    const float* tb = (axis == 0 ? tbl_x : (axis == 1 ? tbl_y : tbl_z));
    v = tb[(((size_t)s * 3 + 1) * LQ + l) * D_ + e];
  }
  Tt[((size_t)(s * 128 + e)) * 256 + c] = v;
}

// bf[s][c] = sum_e qkv_b[s][128+e] * Tt[s][e][c].  grid=2, block=256.
__global__ __launch_bounds__(256) void prep_bf(
    const float* __restrict__ qkv_b, const float* __restrict__ Tt,
    float* __restrict__ bf)
{
  const int s = blockIdx.x, c = threadIdx.x;
  const float* bk = qkv_b + (size_t)s * 384 + 128;
  const float* T  = Tt + (size_t)s * 128 * 256 + c;
  float acc = 0.f;
  #pragma unroll 4
  for (int e = 0; e < 128; e++) acc += bk[e] * T[(size_t)e * 256];
  bf[s * 256 + c] = acc;
}

// ---------------------------------------------------------------------------
// fp32 tiled GEMM (prep only: Wf = Wk @ Tt). grid=(M/64,N/128), block=256.
// ---------------------------------------------------------------------------
__global__ __launch_bounds__(256) void gemm128(
    const float* __restrict__ A, int lda,
    const float* __restrict__ B, int ldb,
    float* __restrict__ C, int ldc)
{
  __shared__ __align__(16) float A_s[16][68];
  __shared__ __align__(16) float B_s[16][132];
  const int t  = threadIdx.x;
  const int m0 = blockIdx.x * 64;
  const int n0 = blockIdx.y * 128;
  const int r  = t >> 2;
  const int kq = (t & 3) * 4;
  const float* arow = A + (size_t)(m0 + r) * lda;
  const int kkb = t >> 4;
  const int cb  = (t & 15) * 8;
  const float* wbase = B + (size_t)kkb * ldb + n0 + cb;
  const int tx = t & 31, ty = t >> 5;

  float acc[8][4];
  #pragma unroll
  for (int i = 0; i < 8; i++)
    #pragma unroll
    for (int j = 0; j < 4; j++) acc[i][j] = 0.f;

  for (int k0 = 0; k0 < 128; k0 += 16) {
    float4 av = *(const float4*)(arow + k0 + kq);
    float4 b0 = *(const float4*)(wbase + (size_t)k0 * ldb);
    float4 b1 = *(const float4*)(wbase + (size_t)k0 * ldb + 4);
    __syncthreads();
    A_s[kq + 0][r] = av.x;
    A_s[kq + 1][r] = av.y;
    A_s[kq + 2][r] = av.z;
    A_s[kq + 3][r] = av.w;
    *(float4*)&B_s[kkb][cb]     = b0;
    *(float4*)&B_s[kkb][cb + 4] = b1;
    __syncthreads();
    #pragma unroll
    for (int kk = 0; kk < 16; kk++) {
      float4 a03 = *(const float4*)&A_s[kk][ty * 8];
      float4 a47 = *(const float4*)&A_s[kk][ty * 8 + 4];
      float4 bv  = *(const float4*)&B_s[kk][tx * 4];
      float a[8] = {a03.x, a03.y, a03.z, a03.w, a47.x, a47.y, a47.z, a47.w};
      float bj[4] = {bv.x, bv.y, bv.z, bv.w};
      #pragma unroll
      for (int i = 0; i < 8; i++)
        #pragma unroll
        for (int j = 0; j < 4; j++)
          acc[i][j] += a[i] * bj[j];
    }
  }
  #pragma unroll
  for (int i = 0; i < 8; i++) {
    float4 o = {acc[i][0], acc[i][1], acc[i][2], acc[i][3]};
    *(float4*)(C + (size_t)(m0 + ty * 8 + i) * ldc + n0 + tx * 4) = o;
  }
}

// ---------------------------------------------------------------------------
// Pack fp32 weight matrix [K x N] (row-major, ld=ldb) into MFMA B-fragment
// layout bf16: frag[(ntile*nsteps + kstep)*64 + lane][j=0..7], where
// B[k][n], n = ntile*16 + (lane&15), k = kstep*32 + (lane>>4)*8 + j.
// grid = ntiles*nsteps, block = 64.
// ---------------------------------------------------------------------------
__global__ __launch_bounds__(64) void pack_bfrag(
    const float* __restrict__ B, int ldb,
    unsigned short* __restrict__ frag, int nsteps)
{
  const int blk = blockIdx.x;
  const int ntile = blk / nsteps, kstep = blk - ntile * nsteps;
  const int lane = threadIdx.x;
  const int n = ntile * 16 + (lane & 15);
  const int kbase = kstep * 32 + (lane >> 4) * 8;
  unsigned v[4];
  #pragma unroll
  for (int h = 0; h < 4; h++) {
    const float x0 = B[(size_t)(kbase + 2 * h) * ldb + n];
    const float x1 = B[(size_t)(kbase + 2 * h + 1) * ldb + n];
    v[h] = f2bf(x0) | ((unsigned)f2bf(x1) << 16);
  }
  uint4 o = {v[0], v[1], v[2], v[3]};
  *(uint4*)(frag + ((size_t)blk * 64 + lane) * 8) = o;
}

// ---------------------------------------------------------------------------
// MFMA qkv+dk GEMM. grid=(MT/64, 5): y<3 -> qkv n-block, y>=3 -> dk n-block.
// Block = 4 waves; wave wr computes rows m0+wr*16.. x 128 cols (8 ntiles).
// No LDS, no barriers. A: row-major bf16 (optional gather). Out fp32 + bias.
// ---------------------------------------------------------------------------
__global__ __launch_bounds__(256) void mfma_qkv_dk(
    const unsigned short* __restrict__ Abf,
    const int* __restrict__ groups,
    const unsigned short* __restrict__ qkvfrag,  // 24 ntiles x 4 ksteps
    const unsigned short* __restrict__ wffrag,   // 16 ntiles x 4 ksteps
    const float* __restrict__ bqkv, const float* __restrict__ bfv,
    float* __restrict__ Cqkv, float* __restrict__ Cdk)
{
  const int t  = threadIdx.x;
  const int m0 = blockIdx.x * 64;
  const int y  = blockIdx.y;
  const bool is_dk = (y >= 3);
  const int n0  = is_dk ? (y - 3) * 128 : y * 128;
  const int ldc = is_dk ? 256 : 384;
  const float* bias = is_dk ? bfv : bqkv;
  float* C          = is_dk ? Cdk : Cqkv;
  const unsigned short* frag = is_dk
      ? (wffrag + (size_t)(y - 3) * 8 * 4 * 64 * 8)
      : (qkvfrag + (size_t)y * 8 * 4 * 64 * 8);

  const int wr = t >> 6, lane = t & 63, quad = lane >> 4, col = lane & 15;
  const int m = m0 + wr * 16 + col;
  const unsigned short* arow;
  if (groups) {
    const int b   = m >> 14;
    const int pid = groups[m];
    arow = Abf + ((size_t)(b << 14) + (size_t)pid) * 128;
  } else {
    arow = Abf + (size_t)m * 128;
  }
  const uint4* bfp = (const uint4*)frag + lane;

  f32x4 acc[8];
  #pragma unroll
  for (int nt = 0; nt < 8; nt++) acc[nt] = (f32x4){0.f, 0.f, 0.f, 0.f};

  #pragma unroll
  for (int ks = 0; ks < 4; ks++) {
    short8 av = as_short8(*(const uint4*)(arow + ks * 32 + quad * 8));
    #pragma unroll
    for (int nt = 0; nt < 8; nt++) {
      short8 bv = as_short8(bfp[(nt * 4 + ks) * 64]);
      acc[nt] = __builtin_amdgcn_mfma_f32_16x16x32_bf16(av, bv, acc[nt], 0, 0, 0);
    }
  }

  const int row0 = m0 + wr * 16 + quad * 4;
  #pragma unroll
  for (int nt = 0; nt < 8; nt++) {
    const int c = n0 + nt * 16 + col;
    const float bsv = bias[c];
    #pragma unroll
    for (int reg = 0; reg < 4; reg++)
      C[(size_t)(row0 + reg) * ldc + c] = acc[nt][reg] + bsv;
  }
}

// ---------------------------------------------------------------------------
// Per-voxel attention, dk precomputed. One block per (b,g). grid=1024.
// fp32 compute; OUTPUT bf16 (only consumers are bf16 MFMA GEMMs).
// ---------------------------------------------------------------------------
__global__ __launch_bounds__(256) void attn2(
    const float* __restrict__ qkv,     // [MT, 384]
    const float* __restrict__ dkb,     // [MT, 256] (cols 0:150 valid)
    const float* __restrict__ coords,  // [B, N, 3]
    const int*   __restrict__ groups,  // [B*N]
    unsigned short* __restrict__ fout) // bf16 [MT, 128]
{
  __shared__ __align__(16) float qk_s[32][260];  // q 0:128, k 128:256; later v 0:128
  __shared__ __align__(16) float dk_s[32 * 152];
  __shared__ float sc_s[32 * 33];
  __shared__ float cs[32][3];

  const int t   = threadIdx.x;
  const int bid = blockIdx.x;
  const int b   = bid >> 9;
  const int g   = bid & 511;
  const size_t mbase = (size_t)bid * 32;

  const int p   = t >> 3;
  const int seg = t & 7;

  {
    const float* src = qkv + (mbase + p) * 384 + seg * 32;
    float* dst = &qk_s[p][seg * 32];
    #pragma unroll
    for (int u = 0; u < 8; u++)
      *(float4*)(dst + u * 4) = *(const float4*)(src + u * 4);
  }
  {
    const float* dkrow = dkb + (mbase + p) * 256;
    #pragma unroll
    for (int u = 0; u < 19; u++) {
      const int c = u * 8 + seg;
      dk_s[p * 152 + c] = dkrow[c];
    }
  }
  if (t < 32) {
    const int pid = groups[(b << 14) + g * KP + t];
    const float* cp = coords + ((size_t)(b << 14) + (size_t)pid) * 3;
    cs[t][0] = cp[0]; cs[t][1] = cp[1]; cs[t][2] = cp[2];
  }
  __syncthreads();

  {
    const int i = p;
    const float cix = cs[i][0], ciy = cs[i][1], ciz = cs[i][2];
    const float* qi  = &qk_s[i][0];
    const float* dki = &dk_s[i * 152];
    float4 s4[4] = {{0,0,0,0},{0,0,0,0},{0,0,0,0},{0,0,0,0}};
    #pragma unroll
    for (int d = 0; d < D_; d += 4) {
      float4 qv = *(const float4*)(qi + d);
      #pragma unroll
      for (int jt = 0; jt < 4; jt++) {
        const float4 kv = *(const float4*)(&qk_s[seg + jt * 8][128 + d]);
        s4[jt].x += qv.x * kv.x; s4[jt].y += qv.y * kv.y;
        s4[jt].z += qv.z * kv.z; s4[jt].w += qv.w * kv.w;
      }
    }
    #pragma unroll
    for (int jt = 0; jt < 4; jt++) {
      const int j = seg + jt * 8;
      const float dot = s4[jt].x + s4[jt].y + s4[jt].z + s4[jt].w;
      float dx = cix - cs[j][0], dy = ciy - cs[j][1], dz = ciz - cs[j][2];
      int ix = (int)floorf((dx + VSF) / QSF);
      int iy = (int)floorf((dy + VSF) / QSF);
      int iz = (int)floorf((dz + VSF) / QSF);
      ix = ix < 0 ? 0 : (ix > 49 ? 49 : ix);
      iy = iy < 0 ? 0 : (iy > 49 ? 49 : iy);
      iz = iz < 0 ? 0 : (iz > 49 ? 49 : iz);
      const float biasv = dki[ix] + dki[50 + iy] + dki[100 + iz];
      sc_s[i * 33 + j] = (dot + biasv) * SCALE;
    }
  }
  __syncthreads();

  {
    const float* src = qkv + (mbase + p) * 384 + 256 + seg * 16;
    float4 v0 = *(const float4*)(src);
    float4 v1 = *(const float4*)(src + 4);
    float4 v2 = *(const float4*)(src + 8);
    float4 v3 = *(const float4*)(src + 12);
    float* dst = &qk_s[p][seg * 16];
    *(float4*)(dst + 0)  = v0;
    *(float4*)(dst + 4)  = v1;
    *(float4*)(dst + 8)  = v2;
    *(float4*)(dst + 12) = v3;
  }
  if (t < 32) {
    float* row = &sc_s[t * 33];
    float mx = row[0];
    #pragma unroll
    for (int j = 1; j < 32; j++) mx = fmaxf(mx, row[j]);
    float sum = 0.f;
    #pragma unroll
    for (int j = 0; j < 32; j++) { float e = __expf(row[j] - mx); row[j] = e; sum += e; }
    const float inv = 1.f / sum;
    #pragma unroll
    for (int j = 0; j < 32; j++) row[j] *= inv;
  }
  __syncthreads();

  {
    const int i = p, es = seg * 16;
    float4 acc0 = {0,0,0,0}, acc1 = {0,0,0,0}, acc2 = {0,0,0,0}, acc3 = {0,0,0,0};
    #pragma unroll 4
    for (int j = 0; j < 32; j++) {
      const float a = sc_s[i * 33 + j];
      const float* vr = &qk_s[j][es];
      float4 v0 = *(const float4*)(vr);
      float4 v1 = *(const float4*)(vr + 4);
      float4 v2 = *(const float4*)(vr + 8);
      float4 v3 = *(const float4*)(vr + 12);
      acc0.x += a * v0.x; acc0.y += a * v0.y; acc0.z += a * v0.z; acc0.w += a * v0.w;
      acc1.x += a * v1.x; acc1.y += a * v1.y; acc1.z += a * v1.z; acc1.w += a * v1.w;
      acc2.x += a * v2.x; acc2.y += a * v2.y; acc2.z += a * v2.z; acc2.w += a * v2.w;
      acc3.x += a * v3.x; acc3.y += a * v3.y; acc3.z += a * v3.z; acc3.w += a * v3.w;
    }
    unsigned short* dst = fout + (mbase + i) * D_ + es;
    uint4 o0, o1;
    o0.x = f2bf(acc0.x) | ((unsigned)f2bf(acc0.y) << 16);
    o0.y = f2bf(acc0.z) | ((unsigned)f2bf(acc0.w) << 16);
    o0.z = f2bf(acc1.x) | ((unsigned)f2bf(acc1.y) << 16);
    o0.w = f2bf(acc1.z) | ((unsigned)f2bf(acc1.w) << 16);
    o1.x = f2bf(acc2.x) | ((unsigned)f2bf(acc2.y) << 16);
    o1.y = f2bf(acc2.z) | ((unsigned)f2bf(acc2.w) << 16);
    o1.z = f2bf(acc3.x) | ((unsigned)f2bf(acc3.y) << 16);
    o1.w = f2bf(acc3.z) | ((unsigned)f2bf(acc3.w) << 16);
    *(uint4*)dst       = o0;
    *(uint4*)(dst + 8) = o1;
  }
}

// ---------------------------------------------------------------------------
// MFMA trans GEMM (K=384) + fused bias/LN/ReLU/maxpool/scatter epilogue.
// grid = MT/64 = 512 blocks, block = 256 (4 waves; wave wr = 16 rows).
// C-fragment layout: row = quad*4+reg, col = lane&15 (per 16-col ntile).
// ---------------------------------------------------------------------------
__global__ __launch_bounds__(256) void trans_mfma(
    const unsigned short* __restrict__ Xbf,
    const int* __restrict__ groups,
    const unsigned short* __restrict__ f1bf,
    const unsigned short* __restrict__ f2bf,
    const unsigned short* __restrict__ Wfrag,   // 8 ntiles x 12 ksteps
    const float* __restrict__ bias, const float* __restrict__ ln_g,
    const float* __restrict__ ln_b,
    float* __restrict__ out_all)
{
  __shared__ float wmax_s[4][128];
  __shared__ float pooled_s[2][128];

  const int t  = threadIdx.x;
  const int m0 = blockIdx.x * 64;
  const int bb = m0 >> 14;
  const int wr = t >> 6, lane = t & 63, quad = lane >> 4, col = lane & 15;

  const int m   = m0 + wr * 16 + col;
  const int pid = groups[m];
  const unsigned short* featrow = Xbf + ((size_t)(bb << 14) + (size_t)pid) * 128;
  const unsigned short* f1row   = f1bf + (size_t)m * 128;
  const unsigned short* f2row   = f2bf + (size_t)m * 128;
  const unsigned short* srcs[3] = {featrow, f1row, f2row};

  const uint4* bfp = (const uint4*)Wfrag + lane;

  f32x4 acc[8];
  #pragma unroll
  for (int nt = 0; nt < 8; nt++) acc[nt] = (f32x4){0.f, 0.f, 0.f, 0.f};

  #pragma unroll
  for (int ks = 0; ks < 12; ks++) {
    const unsigned short* ar = srcs[ks >> 2] + ((ks & 3) * 32 + quad * 8);
    short8 av = as_short8(*(const uint4*)ar);
    #pragma unroll
    for (int nt = 0; nt < 8; nt++) {
      short8 bv = as_short8(bfp[(nt * 12 + ks) * 64]);
      acc[nt] = __builtin_amdgcn_mfma_f32_16x16x32_bf16(av, bv, acc[nt], 0, 0, 0);
    }
  }

  // bias + LayerNorm stats (per row = quad*4+reg; cols live on the 16 lanes
  // of this quad x 8 ntiles) via quad-local shuffles.
  float s[4] = {0.f, 0.f, 0.f, 0.f}, ss[4] = {0.f, 0.f, 0.f, 0.f};
  float gg[8], lb[8];
  #pragma unroll
  for (int nt = 0; nt < 8; nt++) {
    const int c = nt * 16 + col;
    const float bsv = bias[c];
    gg[nt] = ln_g[c]; lb[nt] = ln_b[c];
    #pragma unroll
    for (int reg = 0; reg < 4; reg++) {
      const float v = acc[nt][reg] + bsv;
      acc[nt][reg] = v;
      s[reg] += v; ss[reg] += v * v;
    }
  }
  #pragma unroll
  for (int mk = 1; mk <= 8; mk <<= 1) {
    #pragma unroll
    for (int reg = 0; reg < 4; reg++) {
      s[reg]  += __shfl_xor(s[reg],  mk);
      ss[reg] += __shfl_xor(ss[reg], mk);
    }
  }
  float mu[4], rstd[4];
  #pragma unroll
  for (int reg = 0; reg < 4; reg++) {
    mu[reg] = s[reg] * (1.f / 128.f);
    const float var = ss[reg] * (1.f / 128.f) - mu[reg] * mu[reg];
    rstd[reg] = rsqrtf(var + 1e-5f);
  }
  // LN + ReLU + max over this lane's 4 rows, then max across quads (16 rows)
  float m8[8];
  #pragma unroll
  for (int nt = 0; nt < 8; nt++) {
    float mx = 0.f;   // ReLU floor
    #pragma unroll
    for (int reg = 0; reg < 4; reg++) {
      float v = (acc[nt][reg] - mu[reg]) * rstd[reg] * gg[nt] + lb[nt];
      v = fmaxf(v, 0.f);
      mx = fmaxf(mx, v);
    }
    m8[nt] = mx;
  }
  #pragma unroll
  for (int nt = 0; nt < 8; nt++) {
    m8[nt] = fmaxf(m8[nt], __shfl_xor(m8[nt], 16));
    m8[nt] = fmaxf(m8[nt], __shfl_xor(m8[nt], 32));
  }
  if (quad == 0) {
    #pragma unroll
    for (int nt = 0; nt < 8; nt++) wmax_s[wr][nt * 16 + col] = m8[nt];
  }
  __syncthreads();

  // combine wave pairs -> pooled per voxel; grid-reordered out write
  {
    const int v = t >> 7, c = t & 127;
    const float mx = fmaxf(wmax_s[2 * v][c], wmax_s[2 * v + 1][c]);
    pooled_s[v][c] = mx;
    const int gv = blockIdx.x * 2 + v;
    const int bo = gv >> 9, g = gv & 511;
    const int mm = g >> 6, nn = (g >> 3) & 7, tt2 = g & 7;
    const int opos = tt2 * 64 + nn * 8 + mm;
    out_all[((size_t)bo * G_ + opos) * D_ + c] = mx;
  }
  __syncthreads();

  // scatter pooled to every point (for_ret)
  {
    const int r = t >> 2, qs = (t & 3) * 32, v = r >> 5;
    const int pid2 = groups[m0 + r];
    float* dst = out_all + (size_t)BB * G_ * D_
               + ((size_t)(bb << 14) + (size_t)pid2) * D_ + qs;
    const float* src = &pooled_s[v][qs];
    #pragma unroll
    for (int u = 0; u < 8; u++)
      *(float4*)(dst + u * 4) = *(const float4*)(src + u * 4);
  }
}

// ---------------------------------------------------------------------------
extern "C" void kernel_launch(void* const* d_in, const int* in_sizes, int n_in,
                              void* d_out, int out_size, void* d_ws, size_t ws_size,
                              hipStream_t stream) {
  const float* inputs  = (const float*)d_in[0];
  const float* coords  = (const float*)d_in[1];
  const float* qkv_w   = (const float*)d_in[2];   // [2,128,384]
  const float* qkv_b   = (const float*)d_in[3];   // [2,384]
  const float* tbl_x   = (const float*)d_in[4];   // [2,3,50,128]
  const float* tbl_y   = (const float*)d_in[5];
  const float* tbl_z   = (const float*)d_in[6];
  const float* trans_w = (const float*)d_in[7];   // [384,128]
  const float* trans_b = (const float*)d_in[8];
  const float* ln_g    = (const float*)d_in[9];
  const float* ln_b    = (const float*)d_in[10];
  const int*   groups  = (const int*)d_in[11];    // [2,512,32] flat

  float* out = (float*)d_out;
  float* ws  = (float*)d_ws;
  float* qkvbuf = ws;                                  // MT*384 f32
  float* dkb = qkvbuf + (size_t)MT * 384;              // MT*256 f32
  float* Tt  = dkb + (size_t)MT * 256;                 // 2*128*256 f32
  float* Wf  = Tt + (size_t)2 * 128 * 256;             // 2*128*256 f32
  float* bfv = Wf + (size_t)2 * 128 * 256;             // 2*256 f32
  unsigned short* Xbf  = (unsigned short*)(bfv + 512); // MT*128 bf16
  unsigned short* f1bf = Xbf + (size_t)MT * 128;       // MT*128 bf16
  unsigned short* f2bf = f1bf + (size_t)MT * 128;      // MT*128 bf16
  unsigned short* qkvfrag   = f2bf + (size_t)MT * 128; // 2 * 24*4*64*8
  unsigned short* wffrag    = qkvfrag + 2 * 24 * 4 * 64 * 8;  // 2 * 16*4*64*8
  unsigned short* transfrag = wffrag + 2 * 16 * 4 * 64 * 8;   // 8*12*64*8

  // ---- prep (weights-only work, recomputed every call) ----
  cvt_bf16<<<MT * 128 / (256 * 8), 256, 0, stream>>>(inputs, Xbf);
  prep_tt<<<256, 256, 0, stream>>>(tbl_x, tbl_y, tbl_z, Tt);
  for (int s = 0; s < 2; s++) {
    gemm128<<<dim3(2, 2), 256, 0, stream>>>(
        qkv_w + (size_t)s * 128 * 384 + 128, 384,
        Tt + (size_t)s * 128 * 256, 256,
        Wf + (size_t)s * 128 * 256, 256);
  }
  prep_bf<<<2, 256, 0, stream>>>(qkv_b, Tt, bfv);
  pack_bfrag<<<96, 64, 0, stream>>>(qkv_w, 384, qkvfrag, 4);
  pack_bfrag<<<96, 64, 0, stream>>>(qkv_w + 49152, 384, qkvfrag + 49152, 4);
  pack_bfrag<<<64, 64, 0, stream>>>(Wf, 256, wffrag, 4);
  pack_bfrag<<<64, 64, 0, stream>>>(Wf + 32768, 256, wffrag + 32768, 4);
  pack_bfrag<<<96, 64, 0, stream>>>(trans_w, 128, transfrag, 12);

  // ---- layer 0 ----
  mfma_qkv_dk<<<dim3(MT / 64, 5), 256, 0, stream>>>(
      Xbf, groups, qkvfrag, wffrag, qkv_b, bfv, qkvbuf, dkb);
  attn2<<<BB * G_, 256, 0, stream>>>(qkvbuf, dkb, coords, groups, f1bf);
  // ---- layer 1 ----
  mfma_qkv_dk<<<dim3(MT / 64, 5), 256, 0, stream>>>(
      f1bf, nullptr, qkvfrag + 49152, wffrag + 32768, qkv_b + 384, bfv + 256,
      qkvbuf, dkb);
  attn2<<<BB * G_, 256, 0, stream>>>(qkvbuf, dkb, coords, groups, f2bf);
  // ---- epilogue ----
  trans_mfma<<<MT / 64, 256, 0, stream>>>(Xbf, groups, f1bf, f2bf, transfrag,
                                          trans_b, ln_g, ln_b, out);
}

// Round 5
// 215.628 us; speedup vs baseline: 4.4329x; 1.1919x over previous
//
#include <hip/hip_runtime.h>
#include <cstddef>

// Voxel encoder: B=2, N=16384, G=512 voxels x K=32 pts, d=128, S=2 layers.
// Round 5: qkv/dk inter-kernel buffers in bf16; attention scores via MFMA
// with direct-from-global q/k fragment loads (no LDS staging for q/k);
// attn LDS cut 57KB -> 23KB (5 blocks/CU); prep launches consolidated.

#define D_   128
#define VSF  0.25f
#define QSF  0.01f
#define LQ   50
#define G_   512
#define KP   32
#define BB   2
#define NP   16384
#define MT   32768          // B*N rows
#define SCALE 0.08838834764831845f   // 1/sqrt(128)

using short8 = __attribute__((ext_vector_type(8))) short;
using f32x4  = __attribute__((ext_vector_type(4))) float;

__device__ inline unsigned short f2bf(float x) {
  unsigned u = __builtin_bit_cast(unsigned, x);
  u += 0x7fffu + ((u >> 16) & 1u);      // round-to-nearest-even
  return (unsigned short)(u >> 16);
}
__device__ inline float bu(unsigned short h) {
  return __builtin_bit_cast(float, (unsigned)h << 16);
}
__device__ inline float blo(unsigned w) {
  return __builtin_bit_cast(float, w << 16);
}
__device__ inline float bhi(unsigned w) {
  return __builtin_bit_cast(float, w & 0xffff0000u);
}
__device__ inline short8 as_short8(uint4 v) {
  union { uint4 u; short8 s; } x; x.u = v; return x.s;
}

// ---------------------------------------------------------------------------
// fp32 -> bf16 bulk convert (8 elems/thread). grid = n/(256*8).
// ---------------------------------------------------------------------------
__global__ __launch_bounds__(256) void cvt_bf16(
    const float* __restrict__ in, unsigned short* __restrict__ outp)
{
  const size_t i = ((size_t)blockIdx.x * 256 + threadIdx.x) * 8;
  float4 a = *(const float4*)(in + i);
  float4 b = *(const float4*)(in + i + 4);
  uint4 o;
  o.x = f2bf(a.x) | ((unsigned)f2bf(a.y) << 16);
  o.y = f2bf(a.z) | ((unsigned)f2bf(a.w) << 16);
  o.z = f2bf(b.x) | ((unsigned)f2bf(b.y) << 16);
  o.w = f2bf(b.z) | ((unsigned)f2bf(b.w) << 16);
  *(uint4*)(outp + i) = o;
}

// ---------------------------------------------------------------------------
// Transpose the (s,1) table slices into Tt[s][e=128][c=256], c = axis*50+l,
// zero-padded for c in [150,256). grid = 256 (s*128+e), block = 256 (c).
// ---------------------------------------------------------------------------
__global__ __launch_bounds__(256) void prep_tt(
    const float* __restrict__ tbl_x, const float* __restrict__ tbl_y,
    const float* __restrict__ tbl_z, float* __restrict__ Tt)
{
  const int c = threadIdx.x;
  const int s = blockIdx.x >> 7;
  const int e = blockIdx.x & 127;
  float v = 0.f;
  if (c < 150) {
    const int axis = c / 50, l = c - axis * 50;
    const float* tb = (axis == 0 ? tbl_x : (axis == 1 ? tbl_y : tbl_z));
    v = tb[(((size_t)s * 3 + 1) * LQ + l) * D_ + e];
  }
  Tt[((size_t)(s * 128 + e)) * 256 + c] = v;
}

// bf[s][c] = sum_e qkv_b[s][128+e] * Tt[s][e][c].  grid=2, block=256.
__global__ __launch_bounds__(256) void prep_bf(
    const float* __restrict__ qkv_b, const float* __restrict__ Tt,
    float* __restrict__ bf)
{
  const int s = blockIdx.x, c = threadIdx.x;
  const float* bk = qkv_b + (size_t)s * 384 + 128;
  const float* T  = Tt + (size_t)s * 128 * 256 + c;
  float acc = 0.f;
  #pragma unroll 4
  for (int e = 0; e < 128; e++) acc += bk[e] * T[(size_t)e * 256];
  bf[s * 256 + c] = acc;
}

// ---------------------------------------------------------------------------
// Wf = Wk @ Tt (fp32, both layers in one launch). grid=(2,2,2): x=m, y=n, z=s.
// ---------------------------------------------------------------------------
__global__ __launch_bounds__(256) void wf_gemm(
    const float* __restrict__ qkv_w, const float* __restrict__ Tt,
    float* __restrict__ Wf)
{
  __shared__ __align__(16) float A_s[16][68];
  __shared__ __align__(16) float B_s[16][132];
  const int t  = threadIdx.x;
  const int s  = blockIdx.z;
  const float* A = qkv_w + (size_t)s * 128 * 384 + 128;   // Wk rows, lda=384
  const float* B = Tt + (size_t)s * 128 * 256;            // ldb=256
  float* C       = Wf + (size_t)s * 128 * 256;            // ldc=256
  const int m0 = blockIdx.x * 64;
  const int n0 = blockIdx.y * 128;
  const int r  = t >> 2;
  const int kq = (t & 3) * 4;
  const float* arow = A + (size_t)(m0 + r) * 384;
  const int kkb = t >> 4;
  const int cb  = (t & 15) * 8;
  const float* wbase = B + (size_t)kkb * 256 + n0 + cb;
  const int tx = t & 31, ty = t >> 5;

  float acc[8][4];
  #pragma unroll
  for (int i = 0; i < 8; i++)
    #pragma unroll
    for (int j = 0; j < 4; j++) acc[i][j] = 0.f;

  for (int k0 = 0; k0 < 128; k0 += 16) {
    float4 av = *(const float4*)(arow + k0 + kq);
    float4 b0 = *(const float4*)(wbase + (size_t)k0 * 256);
    float4 b1 = *(const float4*)(wbase + (size_t)k0 * 256 + 4);
    __syncthreads();
    A_s[kq + 0][r] = av.x;
    A_s[kq + 1][r] = av.y;
    A_s[kq + 2][r] = av.z;
    A_s[kq + 3][r] = av.w;
    *(float4*)&B_s[kkb][cb]     = b0;
    *(float4*)&B_s[kkb][cb + 4] = b1;
    __syncthreads();
    #pragma unroll
    for (int kk = 0; kk < 16; kk++) {
      float4 a03 = *(const float4*)&A_s[kk][ty * 8];
      float4 a47 = *(const float4*)&A_s[kk][ty * 8 + 4];
      float4 bv  = *(const float4*)&B_s[kk][tx * 4];
      float a[8] = {a03.x, a03.y, a03.z, a03.w, a47.x, a47.y, a47.z, a47.w};
      float bj[4] = {bv.x, bv.y, bv.z, bv.w};
      #pragma unroll
      for (int i = 0; i < 8; i++)
        #pragma unroll
        for (int j = 0; j < 4; j++)
          acc[i][j] += a[i] * bj[j];
    }
  }
  #pragma unroll
  for (int i = 0; i < 8; i++) {
    float4 o = {acc[i][0], acc[i][1], acc[i][2], acc[i][3]};
    *(float4*)(C + (size_t)(m0 + ty * 8 + i) * 256 + n0 + tx * 4) = o;
  }
}

// ---------------------------------------------------------------------------
// Pack ALL weight matrices into MFMA B-fragment bf16 layout in one launch.
// frag[(ntile*nsteps+kstep)*64 + lane][j], B[k][n]: n=ntile*16+(lane&15),
// k=kstep*32+(lane>>4)*8+j. 416 blocks x 64 threads.
// ---------------------------------------------------------------------------
__global__ __launch_bounds__(64) void pack_all(
    const float* __restrict__ qkv_w, const float* __restrict__ Wf,
    const float* __restrict__ trans_w,
    unsigned short* __restrict__ qkvfrag, unsigned short* __restrict__ wffrag,
    unsigned short* __restrict__ transfrag)
{
  const int blk = blockIdx.x;
  const float* B; int ldb, nsteps, base; unsigned short* dst;
  if (blk < 192) {                 // qkv weights, s=0/1: 24 ntiles x 4 ksteps
    const int s = blk / 96; base = blk - s * 96;
    B = qkv_w + (size_t)s * 128 * 384; ldb = 384; nsteps = 4;
    dst = qkvfrag + (size_t)s * 96 * 512;
  } else if (blk < 320) {          // Wf, s=0/1: 16 ntiles x 4 ksteps
    const int s = (blk - 192) / 64; base = (blk - 192) - s * 64;
    B = Wf + (size_t)s * 32768; ldb = 256; nsteps = 4;
    dst = wffrag + (size_t)s * 64 * 512;
  } else {                         // trans_w: 8 ntiles x 12 ksteps
    base = blk - 320; B = trans_w; ldb = 128; nsteps = 12; dst = transfrag;
  }
  const int ntile = base / nsteps, kstep = base - ntile * nsteps;
  const int lane = threadIdx.x;
  const int n = ntile * 16 + (lane & 15);
  const int kbase = kstep * 32 + (lane >> 4) * 8;
  unsigned v[4];
  #pragma unroll
  for (int h = 0; h < 4; h++) {
    const float x0 = B[(size_t)(kbase + 2 * h) * ldb + n];
    const float x1 = B[(size_t)(kbase + 2 * h + 1) * ldb + n];
    v[h] = f2bf(x0) | ((unsigned)f2bf(x1) << 16);
  }
  uint4 o = {v[0], v[1], v[2], v[3]};
  *(uint4*)(dst + ((size_t)base * 64 + lane) * 8) = o;
}

// ---------------------------------------------------------------------------
// MFMA qkv+dk GEMM, bf16 output. grid=(MT/64, 5): y<3 qkv, y>=3 dk.
// Block = 4 waves; wave wr computes rows m0+wr*16 x 128 cols. No LDS.
// ---------------------------------------------------------------------------
__global__ __launch_bounds__(256) void mfma_qkv_dk(
    const unsigned short* __restrict__ Abf,
    const int* __restrict__ groups,
    const unsigned short* __restrict__ qkvfrag,
    const unsigned short* __restrict__ wffrag,
    const float* __restrict__ bqkv, const float* __restrict__ bfv,
    unsigned short* __restrict__ Cqkv, unsigned short* __restrict__ Cdk)
{
  const int t  = threadIdx.x;
  const int m0 = blockIdx.x * 64;
  const int y  = blockIdx.y;
  const bool is_dk = (y >= 3);
  const int n0  = is_dk ? (y - 3) * 128 : y * 128;
  const int ldc = is_dk ? 256 : 384;
  const float* bias = is_dk ? bfv : bqkv;
  unsigned short* C = is_dk ? Cdk : Cqkv;
  const unsigned short* frag = is_dk
      ? (wffrag + (size_t)(y - 3) * 8 * 4 * 64 * 8)
      : (qkvfrag + (size_t)y * 8 * 4 * 64 * 8);

  const int wr = t >> 6, lane = t & 63, quad = lane >> 4, col = lane & 15;
  const int m = m0 + wr * 16 + col;
  const unsigned short* arow;
  if (groups) {
    const int b   = m >> 14;
    const int pid = groups[m];
    arow = Abf + ((size_t)(b << 14) + (size_t)pid) * 128;
  } else {
    arow = Abf + (size_t)m * 128;
  }
  const uint4* bfp = (const uint4*)frag + lane;

  f32x4 acc[8];
  #pragma unroll
  for (int nt = 0; nt < 8; nt++) acc[nt] = (f32x4){0.f, 0.f, 0.f, 0.f};

  #pragma unroll
  for (int ks = 0; ks < 4; ks++) {
    short8 av = as_short8(*(const uint4*)(arow + ks * 32 + quad * 8));
    #pragma unroll
    for (int nt = 0; nt < 8; nt++) {
      short8 bv = as_short8(bfp[(nt * 4 + ks) * 64]);
      acc[nt] = __builtin_amdgcn_mfma_f32_16x16x32_bf16(av, bv, acc[nt], 0, 0, 0);
    }
  }

  const int row0 = m0 + wr * 16 + quad * 4;
  #pragma unroll
  for (int nt = 0; nt < 8; nt++) {
    const int c = n0 + nt * 16 + col;
    const float bsv = bias[c];
    #pragma unroll
    for (int reg = 0; reg < 4; reg++)
      C[(size_t)(row0 + reg) * ldc + c] = f2bf(acc[nt][reg] + bsv);
  }
}

// ---------------------------------------------------------------------------
// Attention v3. One block (4 waves) per voxel. Scores via MFMA with direct
// global q/k fragment loads; V + dk staged in LDS as bf16; PV in fp32 VALU.
// LDS ~23KB -> 5 blocks/CU. grid=1024, block=256.
// ---------------------------------------------------------------------------
__global__ __launch_bounds__(256, 5) void attn3(
    const unsigned short* __restrict__ qkvB,  // bf16 [MT][384]
    const unsigned short* __restrict__ dkB,   // bf16 [MT][256] (0:150 valid)
    const float* __restrict__ coords,
    const int*   __restrict__ groups,
    unsigned short* __restrict__ fout)        // bf16 [MT][128]
{
  __shared__ float sc_s[32 * 33];
  __shared__ float cs[32][4];
  __shared__ __align__(16) unsigned short dk_s[32 * 152];
  __shared__ __align__(16) unsigned short v_s[32][136];

  const int t   = threadIdx.x;
  const int bid = blockIdx.x;
  const int b   = bid >> 9;
  const int g   = bid & 511;
  const size_t mbase = (size_t)bid * 32;
  const int p = t >> 3, seg = t & 7;

  // ---- stage dk (bf16, 19 x 8-elem chunks per row) ----
  {
    const unsigned short* src = dkB + (mbase + p) * 256;
    #pragma unroll
    for (int u = 0; u < 3; u++) {
      const int ch = u * 8 + seg;
      if (ch < 19)
        *(uint4*)&dk_s[p * 152 + ch * 8] = *(const uint4*)(src + ch * 8);
    }
  }
  // ---- stage V rows (bf16) ----
  {
    const unsigned short* src = qkvB + (mbase + p) * 384 + 256 + seg * 16;
    *(uint4*)&v_s[p][seg * 16]     = *(const uint4*)(src);
    *(uint4*)&v_s[p][seg * 16 + 8] = *(const uint4*)(src + 8);
  }
  if (t < 32) {
    const int pid = groups[(b << 14) + g * KP + t];
    const float* cp = coords + ((size_t)(b << 14) + (size_t)pid) * 3;
    cs[t][0] = cp[0]; cs[t][1] = cp[1]; cs[t][2] = cp[2];
  }

  // ---- scores: S[16x16 tile per wave] = Q @ K^T via MFMA, frags from global
  const int wv = t >> 6, lane = t & 63, quad = lane >> 4, col = lane & 15;
  const int ihalf = wv >> 1, jhalf = wv & 1;
  f32x4 sacc = {0.f, 0.f, 0.f, 0.f};
  {
    const unsigned short* qrow =
        qkvB + (mbase + ihalf * 16 + col) * 384 + quad * 8;
    const unsigned short* krow =
        qkvB + (mbase + jhalf * 16 + col) * 384 + 128 + quad * 8;
    #pragma unroll
    for (int ks = 0; ks < 4; ks++) {
      short8 av = as_short8(*(const uint4*)(qrow + ks * 32));
      short8 bv = as_short8(*(const uint4*)(krow + ks * 32));
      sacc = __builtin_amdgcn_mfma_f32_16x16x32_bf16(av, bv, sacc, 0, 0, 0);
    }
  }
  __syncthreads();   // dk_s / cs staged

  // ---- bias + scale -> sc_s.  C layout: row=quad*4+reg, col=lane&15.
  {
    const int j = jhalf * 16 + col;
    const float cjx = cs[j][0], cjy = cs[j][1], cjz = cs[j][2];
    #pragma unroll
    for (int reg = 0; reg < 4; reg++) {
      const int i = ihalf * 16 + quad * 4 + reg;
      const float dx = cs[i][0] - cjx;
      const float dy = cs[i][1] - cjy;
      const float dz = cs[i][2] - cjz;
      int ix = (int)floorf((dx + VSF) / QSF);
      int iy = (int)floorf((dy + VSF) / QSF);
      int iz = (int)floorf((dz + VSF) / QSF);
      ix = ix < 0 ? 0 : (ix > 49 ? 49 : ix);
      iy = iy < 0 ? 0 : (iy > 49 ? 49 : iy);
      iz = iz < 0 ? 0 : (iz > 49 ? 49 : iz);
      const unsigned short* dki = &dk_s[i * 152];
      const float biasv = bu(dki[ix]) + bu(dki[50 + iy]) + bu(dki[100 + iz]);
      sc_s[i * 33 + j] = (sacc[reg] + biasv) * SCALE;
    }
  }
  __syncthreads();

  // ---- softmax per row (32 threads) ----
  if (t < 32) {
    float* row = &sc_s[t * 33];
    float mx = row[0];
    #pragma unroll
    for (int j = 1; j < 32; j++) mx = fmaxf(mx, row[j]);
    float sum = 0.f;
    #pragma unroll
    for (int j = 0; j < 32; j++) { float e = __expf(row[j] - mx); row[j] = e; sum += e; }
    const float inv = 1.f / sum;
    #pragma unroll
    for (int j = 0; j < 32; j++) row[j] *= inv;
  }
  __syncthreads();

  // ---- PV (fp32 VALU, V bf16 from LDS) ----
  {
    const int es = seg * 16;
    float acc[16];
    #pragma unroll
    for (int k = 0; k < 16; k++) acc[k] = 0.f;
    #pragma unroll 4
    for (int j = 0; j < 32; j++) {
      const float a = sc_s[p * 33 + j];
      const uint4 u0 = *(const uint4*)&v_s[j][es];
      const uint4 u1 = *(const uint4*)&v_s[j][es + 8];
      acc[0]  += a * blo(u0.x); acc[1]  += a * bhi(u0.x);
      acc[2]  += a * blo(u0.y); acc[3]  += a * bhi(u0.y);
      acc[4]  += a * blo(u0.z); acc[5]  += a * bhi(u0.z);
      acc[6]  += a * blo(u0.w); acc[7]  += a * bhi(u0.w);
      acc[8]  += a * blo(u1.x); acc[9]  += a * bhi(u1.x);
      acc[10] += a * blo(u1.y); acc[11] += a * bhi(u1.y);
      acc[12] += a * blo(u1.z); acc[13] += a * bhi(u1.z);
      acc[14] += a * blo(u1.w); acc[15] += a * bhi(u1.w);
    }
    unsigned short* dst = fout + (mbase + p) * D_ + es;
    uint4 o0, o1;
    o0.x = f2bf(acc[0])  | ((unsigned)f2bf(acc[1])  << 16);
    o0.y = f2bf(acc[2])  | ((unsigned)f2bf(acc[3])  << 16);
    o0.z = f2bf(acc[4])  | ((unsigned)f2bf(acc[5])  << 16);
    o0.w = f2bf(acc[6])  | ((unsigned)f2bf(acc[7])  << 16);
    o1.x = f2bf(acc[8])  | ((unsigned)f2bf(acc[9])  << 16);
    o1.y = f2bf(acc[10]) | ((unsigned)f2bf(acc[11]) << 16);
    o1.z = f2bf(acc[12]) | ((unsigned)f2bf(acc[13]) << 16);
    o1.w = f2bf(acc[14]) | ((unsigned)f2bf(acc[15]) << 16);
    *(uint4*)dst       = o0;
    *(uint4*)(dst + 8) = o1;
  }
}

// ---------------------------------------------------------------------------
// MFMA trans GEMM (K=384) + fused bias/LN/ReLU/maxpool/scatter epilogue.
// grid = MT/64 = 512 blocks, block = 256 (4 waves; wave wr = 16 rows).
// ---------------------------------------------------------------------------
__global__ __launch_bounds__(256) void trans_mfma(
    const unsigned short* __restrict__ Xbf,
    const int* __restrict__ groups,
    const unsigned short* __restrict__ f1bf,
    const unsigned short* __restrict__ f2bf,
    const unsigned short* __restrict__ Wfrag,   // 8 ntiles x 12 ksteps
    const float* __restrict__ bias, const float* __restrict__ ln_g,
    const float* __restrict__ ln_b,
    float* __restrict__ out_all)
{
  __shared__ float wmax_s[4][128];
  __shared__ float pooled_s[2][128];

  const int t  = threadIdx.x;
  const int m0 = blockIdx.x * 64;
  const int bb = m0 >> 14;
  const int wr = t >> 6, lane = t & 63, quad = lane >> 4, col = lane & 15;

  const int m   = m0 + wr * 16 + col;
  const int pid = groups[m];
  const unsigned short* featrow = Xbf + ((size_t)(bb << 14) + (size_t)pid) * 128;
  const unsigned short* f1row   = f1bf + (size_t)m * 128;
  const unsigned short* f2row   = f2bf + (size_t)m * 128;
  const unsigned short* srcs[3] = {featrow, f1row, f2row};

  const uint4* bfp = (const uint4*)Wfrag + lane;

  f32x4 acc[8];
  #pragma unroll
  for (int nt = 0; nt < 8; nt++) acc[nt] = (f32x4){0.f, 0.f, 0.f, 0.f};

  #pragma unroll
  for (int ks = 0; ks < 12; ks++) {
    const unsigned short* ar = srcs[ks >> 2] + ((ks & 3) * 32 + quad * 8);
    short8 av = as_short8(*(const uint4*)ar);
    #pragma unroll
    for (int nt = 0; nt < 8; nt++) {
      short8 bv = as_short8(bfp[(nt * 12 + ks) * 64]);
      acc[nt] = __builtin_amdgcn_mfma_f32_16x16x32_bf16(av, bv, acc[nt], 0, 0, 0);
    }
  }

  float s[4] = {0.f, 0.f, 0.f, 0.f}, ss[4] = {0.f, 0.f, 0.f, 0.f};
  float gg[8], lb[8];
  #pragma unroll
  for (int nt = 0; nt < 8; nt++) {
    const int c = nt * 16 + col;
    const float bsv = bias[c];
    gg[nt] = ln_g[c]; lb[nt] = ln_b[c];
    #pragma unroll
    for (int reg = 0; reg < 4; reg++) {
      const float v = acc[nt][reg] + bsv;
      acc[nt][reg] = v;
      s[reg] += v; ss[reg] += v * v;
    }
  }
  #pragma unroll
  for (int mk = 1; mk <= 8; mk <<= 1) {
    #pragma unroll
    for (int reg = 0; reg < 4; reg++) {
      s[reg]  += __shfl_xor(s[reg],  mk);
      ss[reg] += __shfl_xor(ss[reg], mk);
    }
  }
  float mu[4], rstd[4];
  #pragma unroll
  for (int reg = 0; reg < 4; reg++) {
    mu[reg] = s[reg] * (1.f / 128.f);
    const float var = ss[reg] * (1.f / 128.f) - mu[reg] * mu[reg];
    rstd[reg] = rsqrtf(var + 1e-5f);
  }
  float m8[8];
  #pragma unroll
  for (int nt = 0; nt < 8; nt++) {
    float mx = 0.f;   // ReLU floor
    #pragma unroll
    for (int reg = 0; reg < 4; reg++) {
      float v = (acc[nt][reg] - mu[reg]) * rstd[reg] * gg[nt] + lb[nt];
      v = fmaxf(v, 0.f);
      mx = fmaxf(mx, v);
    }
    m8[nt] = mx;
  }
  #pragma unroll
  for (int nt = 0; nt < 8; nt++) {
    m8[nt] = fmaxf(m8[nt], __shfl_xor(m8[nt], 16));
    m8[nt] = fmaxf(m8[nt], __shfl_xor(m8[nt], 32));
  }
  if (quad == 0) {
    #pragma unroll
    for (int nt = 0; nt < 8; nt++) wmax_s[wr][nt * 16 + col] = m8[nt];
  }
  __syncthreads();

  {
    const int v = t >> 7, c = t & 127;
    const float mx = fmaxf(wmax_s[2 * v][c], wmax_s[2 * v + 1][c]);
    pooled_s[v][c] = mx;
    const int gv = blockIdx.x * 2 + v;
    const int bo = gv >> 9, g = gv & 511;
    const int mm = g >> 6, nn = (g >> 3) & 7, tt2 = g & 7;
    const int opos = tt2 * 64 + nn * 8 + mm;
    out_all[((size_t)bo * G_ + opos) * D_ + c] = mx;
  }
  __syncthreads();

  {
    const int r = t >> 2, qs = (t & 3) * 32, v = r >> 5;
    const int pid2 = groups[m0 + r];
    float* dst = out_all + (size_t)BB * G_ * D_
               + ((size_t)(bb << 14) + (size_t)pid2) * D_ + qs;
    const float* src = &pooled_s[v][qs];
    #pragma unroll
    for (int u = 0; u < 8; u++)
      *(float4*)(dst + u * 4) = *(const float4*)(src + u * 4);
  }
}

// ---------------------------------------------------------------------------
extern "C" void kernel_launch(void* const* d_in, const int* in_sizes, int n_in,
                              void* d_out, int out_size, void* d_ws, size_t ws_size,
                              hipStream_t stream) {
  const float* inputs  = (const float*)d_in[0];
  const float* coords  = (const float*)d_in[1];
  const float* qkv_w   = (const float*)d_in[2];   // [2,128,384]
  const float* qkv_b   = (const float*)d_in[3];   // [2,384]
  const float* tbl_x   = (const float*)d_in[4];   // [2,3,50,128]
  const float* tbl_y   = (const float*)d_in[5];
  const float* tbl_z   = (const float*)d_in[6];
  const float* trans_w = (const float*)d_in[7];   // [384,128]
  const float* trans_b = (const float*)d_in[8];
  const float* ln_g    = (const float*)d_in[9];
  const float* ln_b    = (const float*)d_in[10];
  const int*   groups  = (const int*)d_in[11];    // [2,512,32] flat

  float* out = (float*)d_out;
  // workspace layout (16B-aligned chunks)
  unsigned short* qkvB = (unsigned short*)d_ws;            // MT*384 bf16
  unsigned short* dkB  = qkvB + (size_t)MT * 384;          // MT*256 bf16
  unsigned short* Xbf  = dkB + (size_t)MT * 256;           // MT*128 bf16
  unsigned short* f1bf = Xbf + (size_t)MT * 128;           // MT*128 bf16
  unsigned short* f2bf = f1bf + (size_t)MT * 128;          // MT*128 bf16
  unsigned short* qkvfrag   = f2bf + (size_t)MT * 128;     // 2*96*512
  unsigned short* wffrag    = qkvfrag + 2 * 96 * 512;      // 2*64*512
  unsigned short* transfrag = wffrag + 2 * 64 * 512;       // 96*512
  float* Tt  = (float*)(transfrag + 96 * 512);             // 2*128*256 f32
  float* Wf  = Tt + (size_t)2 * 128 * 256;                 // 2*128*256 f32
  float* bfv = Wf + (size_t)2 * 128 * 256;                 // 2*256 f32

  // ---- prep ----
  cvt_bf16<<<MT * 128 / (256 * 8), 256, 0, stream>>>(inputs, Xbf);
  prep_tt<<<256, 256, 0, stream>>>(tbl_x, tbl_y, tbl_z, Tt);
  wf_gemm<<<dim3(2, 2, 2), 256, 0, stream>>>(qkv_w, Tt, Wf);
  prep_bf<<<2, 256, 0, stream>>>(qkv_b, Tt, bfv);
  pack_all<<<416, 64, 0, stream>>>(qkv_w, Wf, trans_w,
                                   qkvfrag, wffrag, transfrag);

  // ---- layer 0 ----
  mfma_qkv_dk<<<dim3(MT / 64, 5), 256, 0, stream>>>(
      Xbf, groups, qkvfrag, wffrag, qkv_b, bfv, qkvB, dkB);
  attn3<<<BB * G_, 256, 0, stream>>>(qkvB, dkB, coords, groups, f1bf);
  // ---- layer 1 ----
  mfma_qkv_dk<<<dim3(MT / 64, 5), 256, 0, stream>>>(
      f1bf, nullptr, qkvfrag + 96 * 512, wffrag + 64 * 512, qkv_b + 384,
      bfv + 256, qkvB, dkB);
  attn3<<<BB * G_, 256, 0, stream>>>(qkvB, dkB, coords, groups, f2bf);
  // ---- epilogue ----
  trans_mfma<<<MT / 64, 256, 0, stream>>>(Xbf, groups, f1bf, f2bf, transfrag,
                                          trans_b, ln_g, ln_b, out);
}

// Round 6
// 193.136 us; speedup vs baseline: 4.9491x; 1.1165x over previous
//
#include <hip/hip_runtime.h>
#include <cstddef>

// Voxel encoder: B=2, N=16384, G=512 voxels x K=32 pts, d=128, S=2 layers.
// Round 6: per-voxel FUSED layer kernel — one block computes qkv+dk (MFMA,
// weights from L2-hot fragment buffers, 544 output cols) into LDS, then
// scores (MFMA from LDS frags) + softmax + PV in the same block. Removes the
// 42MB/layer qkvB/dkB HBM round-trip and two dispatches per layer.

#define D_   128
#define VSF  0.25f
#define QSF  0.01f
#define LQ   50
#define G_   512
#define KP   32
#define BB   2
#define NP   16384
#define MT   32768          // B*N rows
#define SCALE 0.08838834764831845f   // 1/sqrt(128)
#define NT_ALL 34           // 24 qkv tiles + 10 dk tiles (cols 0..543)
#define FRAG_S (NT_ALL * 4 * 64 * 8)   // ushorts per layer frag buffer

using short8 = __attribute__((ext_vector_type(8))) short;
using f32x4  = __attribute__((ext_vector_type(4))) float;

__device__ inline unsigned short f2bf(float x) {
  unsigned u = __builtin_bit_cast(unsigned, x);
  u += 0x7fffu + ((u >> 16) & 1u);      // round-to-nearest-even
  return (unsigned short)(u >> 16);
}
__device__ inline float bu(unsigned short h) {
  return __builtin_bit_cast(float, (unsigned)h << 16);
}
__device__ inline float blo(unsigned w) {
  return __builtin_bit_cast(float, w << 16);
}
__device__ inline float bhi(unsigned w) {
  return __builtin_bit_cast(float, w & 0xffff0000u);
}
__device__ inline short8 as_short8(uint4 v) {
  union { uint4 u; short8 s; } x; x.u = v; return x.s;
}

// ---------------------------------------------------------------------------
// fp32 -> bf16 bulk convert (8 elems/thread). grid = n/(256*8).
// ---------------------------------------------------------------------------
__global__ __launch_bounds__(256) void cvt_bf16(
    const float* __restrict__ in, unsigned short* __restrict__ outp)
{
  const size_t i = ((size_t)blockIdx.x * 256 + threadIdx.x) * 8;
  float4 a = *(const float4*)(in + i);
  float4 b = *(const float4*)(in + i + 4);
  uint4 o;
  o.x = f2bf(a.x) | ((unsigned)f2bf(a.y) << 16);
  o.y = f2bf(a.z) | ((unsigned)f2bf(a.w) << 16);
  o.z = f2bf(b.x) | ((unsigned)f2bf(b.y) << 16);
  o.w = f2bf(b.z) | ((unsigned)f2bf(b.w) << 16);
  *(uint4*)(outp + i) = o;
}

// ---------------------------------------------------------------------------
// Transpose the (s,1) table slices into Tt[s][e=128][c=256], c = axis*50+l,
// zero-padded for c in [150,256). grid = 256 (s*128+e), block = 256 (c).
// ---------------------------------------------------------------------------
__global__ __launch_bounds__(256) void prep_tt(
    const float* __restrict__ tbl_x, const float* __restrict__ tbl_y,
    const float* __restrict__ tbl_z, float* __restrict__ Tt)
{
  const int c = threadIdx.x;
  const int s = blockIdx.x >> 7;
  const int e = blockIdx.x & 127;
  float v = 0.f;
  if (c < 150) {
    const int axis = c / 50, l = c - axis * 50;
    const float* tb = (axis == 0 ? tbl_x : (axis == 1 ? tbl_y : tbl_z));
    v = tb[(((size_t)s * 3 + 1) * LQ + l) * D_ + e];
  }
  Tt[((size_t)(s * 128 + e)) * 256 + c] = v;
}

// ---------------------------------------------------------------------------
// Wf = Wk @ Tt (fp32, both layers). grid=(2,2,2): x=m-tile, y=n-tile, z=s.
// ---------------------------------------------------------------------------
__global__ __launch_bounds__(256) void wf_gemm(
    const float* __restrict__ qkv_w, const float* __restrict__ Tt,
    float* __restrict__ Wf)
{
  __shared__ __align__(16) float A_s[16][68];
  __shared__ __align__(16) float B_s[16][132];
  const int t  = threadIdx.x;
  const int s  = blockIdx.z;
  const float* A = qkv_w + (size_t)s * 128 * 384 + 128;   // Wk rows, lda=384
  const float* B = Tt + (size_t)s * 128 * 256;            // ldb=256
  float* C       = Wf + (size_t)s * 128 * 256;            // ldc=256
  const int m0 = blockIdx.x * 64;
  const int n0 = blockIdx.y * 128;
  const int r  = t >> 2;
  const int kq = (t & 3) * 4;
  const float* arow = A + (size_t)(m0 + r) * 384;
  const int kkb = t >> 4;
  const int cb  = (t & 15) * 8;
  const float* wbase = B + (size_t)kkb * 256 + n0 + cb;
  const int tx = t & 31, ty = t >> 5;

  float acc[8][4];
  #pragma unroll
  for (int i = 0; i < 8; i++)
    #pragma unroll
    for (int j = 0; j < 4; j++) acc[i][j] = 0.f;

  for (int k0 = 0; k0 < 128; k0 += 16) {
    float4 av = *(const float4*)(arow + k0 + kq);
    float4 b0 = *(const float4*)(wbase + (size_t)k0 * 256);
    float4 b1 = *(const float4*)(wbase + (size_t)k0 * 256 + 4);
    __syncthreads();
    A_s[kq + 0][r] = av.x;
    A_s[kq + 1][r] = av.y;
    A_s[kq + 2][r] = av.z;
    A_s[kq + 3][r] = av.w;
    *(float4*)&B_s[kkb][cb]     = b0;
    *(float4*)&B_s[kkb][cb + 4] = b1;
    __syncthreads();
    #pragma unroll
    for (int kk = 0; kk < 16; kk++) {
      float4 a03 = *(const float4*)&A_s[kk][ty * 8];
      float4 a47 = *(const float4*)&A_s[kk][ty * 8 + 4];
      float4 bv  = *(const float4*)&B_s[kk][tx * 4];
      float a[8] = {a03.x, a03.y, a03.z, a03.w, a47.x, a47.y, a47.z, a47.w};
      float bj[4] = {bv.x, bv.y, bv.z, bv.w};
      #pragma unroll
      for (int i = 0; i < 8; i++)
        #pragma unroll
        for (int j = 0; j < 4; j++)
          acc[i][j] += a[i] * bj[j];
    }
  }
  #pragma unroll
  for (int i = 0; i < 8; i++) {
    float4 o = {acc[i][0], acc[i][1], acc[i][2], acc[i][3]};
    *(float4*)(C + (size_t)(m0 + ty * 8 + i) * 256 + n0 + tx * 4) = o;
  }
}

// ---------------------------------------------------------------------------
// pack2: all fragment packing + combined bias in one launch. 370 blocks x 64.
//  blk <192 : qkv_w s=blk/96      -> allfrag[s] ntiles 0..23
//  blk <272 : Wf    s=(blk-192)/40-> allfrag[s] ntiles 24..33
//  blk <368 : trans_w             -> transfrag (8 nt x 12 ks)
//  else     : combined bias bc[s][544] = [qkv_b | bk@Tt]
// frag layout: dst[((nt*nsteps+ks)*64+lane)*8 + j], B[k][n]:
//   n = snt*16+(lane&15), k = ks*32+(lane>>4)*8+j.
// ---------------------------------------------------------------------------
__global__ __launch_bounds__(64) void pack2(
    const float* __restrict__ qkv_w, const float* __restrict__ Wf,
    const float* __restrict__ trans_w, const float* __restrict__ qkv_b,
    const float* __restrict__ Tt,
    unsigned short* __restrict__ allfrag,
    unsigned short* __restrict__ transfrag,
    float* __restrict__ bc)
{
  const int blk = blockIdx.x;
  const int lane = threadIdx.x;
  const float* B; int ldb, dstidx; unsigned short* dst; int kbase, n;
  if (blk < 192) {
    const int s = blk / 96, r = blk - s * 96;
    const int nt = r >> 2, ks = r & 3;
    B = qkv_w + (size_t)s * 128 * 384; ldb = 384;
    n = nt * 16 + (lane & 15);
    kbase = ks * 32 + ((lane >> 4) * 8);
    dst = allfrag + (size_t)s * FRAG_S;
    dstidx = nt * 4 + ks;
  } else if (blk < 272) {
    const int s = (blk - 192) / 40, r = (blk - 192) - s * 40;
    const int snt = r >> 2, ks = r & 3;
    B = Wf + (size_t)s * 32768; ldb = 256;
    n = snt * 16 + (lane & 15);
    kbase = ks * 32 + ((lane >> 4) * 8);
    dst = allfrag + (size_t)s * FRAG_S;
    dstidx = (24 + snt) * 4 + ks;
  } else if (blk < 368) {
    const int r = blk - 272;
    const int nt = r / 12, ks = r - nt * 12;
    B = trans_w; ldb = 128;
    n = nt * 16 + (lane & 15);
    kbase = ks * 32 + ((lane >> 4) * 8);
    dst = transfrag;
    dstidx = nt * 12 + ks;
  } else {
    const int s = blk - 368;
    for (int c = lane; c < 544; c += 64) {
      float v;
      if (c < 384) {
        v = qkv_b[s * 384 + c];
      } else {
        const float* bk = qkv_b + (size_t)s * 384 + 128;
        const float* T  = Tt + (size_t)s * 128 * 256 + (c - 384);
        float a = 0.f;
        #pragma unroll 4
        for (int e = 0; e < 128; e++) a += bk[e] * T[(size_t)e * 256];
        v = a;
      }
      bc[s * 544 + c] = v;
    }
    return;
  }
  unsigned v[4];
  #pragma unroll
  for (int h = 0; h < 4; h++) {
    const float x0 = B[(size_t)(kbase + 2 * h) * ldb + n];
    const float x1 = B[(size_t)(kbase + 2 * h + 1) * ldb + n];
    v[h] = f2bf(x0) | ((unsigned)f2bf(x1) << 16);
  }
  uint4 o = {v[0], v[1], v[2], v[3]};
  *(uint4*)(dst + ((size_t)dstidx * 64 + lane) * 8) = o;
}

// ---------------------------------------------------------------------------
// Fused layer: one block (4 waves) per voxel.
//  Phase A: qkv+dk GEMM (32 rows x 544 cols, K=128) via MFMA; A frags from
//           global bf16 (optional gather), B frags from L2-hot allfrag;
//           result (bias added) -> LDS bf16 qkv_s[32][552].
//  Phase B: scores = Q@K^T via MFMA from LDS frags; +dk bias lookups; softmax;
//           PV (fp32 VALU, V from LDS); write f out bf16.
// grid = 1024, block = 256. LDS ~40KB -> 4 blocks/CU.
// ---------------------------------------------------------------------------
__global__ __launch_bounds__(256, 4) void layer_fused(
    const unsigned short* __restrict__ Abf,
    const int* __restrict__ groups, int gatherA,
    const unsigned short* __restrict__ allfrag,  // this layer's 34x4 frags
    const float* __restrict__ bc,                // this layer's 544 bias
    const float* __restrict__ coords,
    unsigned short* __restrict__ fout)           // bf16 [MT][128]
{
  __shared__ __align__(16) unsigned short qkv_s[32][552];
  __shared__ float sc_s[32 * 33];
  __shared__ float cs[32][4];

  const int t   = threadIdx.x;
  const int bid = blockIdx.x;
  const int b   = bid >> 9;
  const int g   = bid & 511;
  const size_t mbase = (size_t)bid * 32;
  const int wv = t >> 6, lane = t & 63, quad = lane >> 4, col = lane & 15;

  // coords staging (overlaps phase A)
  if (t < 32) {
    const int pid = groups[(b << 14) + g * KP + t];
    const float* cp = coords + ((size_t)(b << 14) + (size_t)pid) * 3;
    cs[t][0] = cp[0]; cs[t][1] = cp[1]; cs[t][2] = cp[2];
  }

  // ---- Phase A: qkv+dk GEMM ----
  const unsigned short* arow[2];
  #pragma unroll
  for (int rt = 0; rt < 2; rt++) {
    const int m = (int)mbase + rt * 16 + col;
    if (gatherA) {
      const int pid = groups[m];
      arow[rt] = Abf + ((size_t)(b << 14) + (size_t)pid) * 128;
    } else {
      arow[rt] = Abf + (size_t)m * 128;
    }
  }

  const int starts[4] = {0, 9, 18, 26};
  const int start = starts[wv];
  const int cnt = (wv < 2) ? 9 : 8;

  f32x4 acc[9][2];
  #pragma unroll
  for (int u = 0; u < 9; u++) {
    acc[u][0] = (f32x4){0.f, 0.f, 0.f, 0.f};
    acc[u][1] = (f32x4){0.f, 0.f, 0.f, 0.f};
  }

  const uint4* fr = (const uint4*)allfrag + lane;
  #pragma unroll
  for (int ks = 0; ks < 4; ks++) {
    short8 av0 = as_short8(*(const uint4*)(arow[0] + ks * 32 + quad * 8));
    short8 av1 = as_short8(*(const uint4*)(arow[1] + ks * 32 + quad * 8));
    #pragma unroll
    for (int u = 0; u < 9; u++) {
      if (u < cnt) {
        const int nt = start + u;
        short8 bv = as_short8(fr[(nt * 4 + ks) * 64]);
        acc[u][0] = __builtin_amdgcn_mfma_f32_16x16x32_bf16(av0, bv, acc[u][0], 0, 0, 0);
        acc[u][1] = __builtin_amdgcn_mfma_f32_16x16x32_bf16(av1, bv, acc[u][1], 0, 0, 0);
      }
    }
  }

  // epilogue: +bias, bf16, -> LDS (C layout: row=rt*16+quad*4+reg, col=cc)
  #pragma unroll
  for (int u = 0; u < 9; u++) {
    if (u < cnt) {
      const int cc = (start + u) * 16 + col;
      const float bsv = bc[cc];
      #pragma unroll
      for (int rt = 0; rt < 2; rt++) {
        #pragma unroll
        for (int reg = 0; reg < 4; reg++) {
          qkv_s[rt * 16 + quad * 4 + reg][cc] = f2bf(acc[u][rt][reg] + bsv);
        }
      }
    }
  }
  __syncthreads();

  // ---- Phase B: scores via MFMA from LDS frags ----
  const int ihalf = wv >> 1, jhalf = wv & 1;
  f32x4 sacc = {0.f, 0.f, 0.f, 0.f};
  #pragma unroll
  for (int ks = 0; ks < 4; ks++) {
    short8 qv = as_short8(*(const uint4*)&qkv_s[ihalf * 16 + col][ks * 32 + quad * 8]);
    short8 kv = as_short8(*(const uint4*)&qkv_s[jhalf * 16 + col][128 + ks * 32 + quad * 8]);
    sacc = __builtin_amdgcn_mfma_f32_16x16x32_bf16(qv, kv, sacc, 0, 0, 0);
  }
  // bias + scale -> sc_s
  {
    const int j = jhalf * 16 + col;
    const float cjx = cs[j][0], cjy = cs[j][1], cjz = cs[j][2];
    #pragma unroll
    for (int reg = 0; reg < 4; reg++) {
      const int i = ihalf * 16 + quad * 4 + reg;
      const float dx = cs[i][0] - cjx;
      const float dy = cs[i][1] - cjy;
      const float dz = cs[i][2] - cjz;
      int ix = (int)floorf((dx + VSF) / QSF);
      int iy = (int)floorf((dy + VSF) / QSF);
      int iz = (int)floorf((dz + VSF) / QSF);
      ix = ix < 0 ? 0 : (ix > 49 ? 49 : ix);
      iy = iy < 0 ? 0 : (iy > 49 ? 49 : iy);
      iz = iz < 0 ? 0 : (iz > 49 ? 49 : iz);
      const unsigned short* dki = &qkv_s[i][384];
      const float biasv = bu(dki[ix]) + bu(dki[50 + iy]) + bu(dki[100 + iz]);
      sc_s[i * 33 + j] = (sacc[reg] + biasv) * SCALE;
    }
  }
  __syncthreads();

  // softmax per row (32 threads)
  if (t < 32) {
    float* row = &sc_s[t * 33];
    float mx = row[0];
    #pragma unroll
    for (int j = 1; j < 32; j++) mx = fmaxf(mx, row[j]);
    float sum = 0.f;
    #pragma unroll
    for (int j = 0; j < 32; j++) { float e = __expf(row[j] - mx); row[j] = e; sum += e; }
    const float inv = 1.f / sum;
    #pragma unroll
    for (int j = 0; j < 32; j++) row[j] *= inv;
  }
  __syncthreads();

  // PV (fp32 VALU, V bf16 from LDS cols 256..383)
  {
    const int p = t >> 3, seg = t & 7, es = seg * 16;
    float acc2[16];
    #pragma unroll
    for (int k = 0; k < 16; k++) acc2[k] = 0.f;
    #pragma unroll 4
    for (int j = 0; j < 32; j++) {
      const float a = sc_s[p * 33 + j];
      const uint4 u0 = *(const uint4*)&qkv_s[j][256 + es];
      const uint4 u1 = *(const uint4*)&qkv_s[j][256 + es + 8];
      acc2[0]  += a * blo(u0.x); acc2[1]  += a * bhi(u0.x);
      acc2[2]  += a * blo(u0.y); acc2[3]  += a * bhi(u0.y);
      acc2[4]  += a * blo(u0.z); acc2[5]  += a * bhi(u0.z);
      acc2[6]  += a * blo(u0.w); acc2[7]  += a * bhi(u0.w);
      acc2[8]  += a * blo(u1.x); acc2[9]  += a * bhi(u1.x);
      acc2[10] += a * blo(u1.y); acc2[11] += a * bhi(u1.y);
      acc2[12] += a * blo(u1.z); acc2[13] += a * bhi(u1.z);
      acc2[14] += a * blo(u1.w); acc2[15] += a * bhi(u1.w);
    }
    unsigned short* dst = fout + (mbase + p) * D_ + es;
    uint4 o0, o1;
    o0.x = f2bf(acc2[0])  | ((unsigned)f2bf(acc2[1])  << 16);
    o0.y = f2bf(acc2[2])  | ((unsigned)f2bf(acc2[3])  << 16);
    o0.z = f2bf(acc2[4])  | ((unsigned)f2bf(acc2[5])  << 16);
    o0.w = f2bf(acc2[6])  | ((unsigned)f2bf(acc2[7])  << 16);
    o1.x = f2bf(acc2[8])  | ((unsigned)f2bf(acc2[9])  << 16);
    o1.y = f2bf(acc2[10]) | ((unsigned)f2bf(acc2[11]) << 16);
    o1.z = f2bf(acc2[12]) | ((unsigned)f2bf(acc2[13]) << 16);
    o1.w = f2bf(acc2[14]) | ((unsigned)f2bf(acc2[15]) << 16);
    *(uint4*)dst       = o0;
    *(uint4*)(dst + 8) = o1;
  }
}

// ---------------------------------------------------------------------------
// MFMA trans GEMM (K=384) + fused bias/LN/ReLU/maxpool/scatter epilogue.
// grid = MT/64 = 512 blocks, block = 256 (4 waves; wave wr = 16 rows).
// ---------------------------------------------------------------------------
__global__ __launch_bounds__(256) void trans_mfma(
    const unsigned short* __restrict__ Xbf,
    const int* __restrict__ groups,
    const unsigned short* __restrict__ f1bf,
    const unsigned short* __restrict__ f2bf,
    const unsigned short* __restrict__ Wfrag,   // 8 ntiles x 12 ksteps
    const float* __restrict__ bias, const float* __restrict__ ln_g,
    const float* __restrict__ ln_b,
    float* __restrict__ out_all)
{
  __shared__ float wmax_s[4][128];
  __shared__ float pooled_s[2][128];

  const int t  = threadIdx.x;
  const int m0 = blockIdx.x * 64;
  const int bb = m0 >> 14;
  const int wr = t >> 6, lane = t & 63, quad = lane >> 4, col = lane & 15;

  const int m   = m0 + wr * 16 + col;
  const int pid = groups[m];
  const unsigned short* featrow = Xbf + ((size_t)(bb << 14) + (size_t)pid) * 128;
  const unsigned short* f1row   = f1bf + (size_t)m * 128;
  const unsigned short* f2row   = f2bf + (size_t)m * 128;
  const unsigned short* srcs[3] = {featrow, f1row, f2row};

  const uint4* bfp = (const uint4*)Wfrag + lane;

  f32x4 acc[8];
  #pragma unroll
  for (int nt = 0; nt < 8; nt++) acc[nt] = (f32x4){0.f, 0.f, 0.f, 0.f};

  #pragma unroll
  for (int ks = 0; ks < 12; ks++) {
    const unsigned short* ar = srcs[ks >> 2] + ((ks & 3) * 32 + quad * 8);
    short8 av = as_short8(*(const uint4*)ar);
    #pragma unroll
    for (int nt = 0; nt < 8; nt++) {
      short8 bv = as_short8(bfp[(nt * 12 + ks) * 64]);
      acc[nt] = __builtin_amdgcn_mfma_f32_16x16x32_bf16(av, bv, acc[nt], 0, 0, 0);
    }
  }

  float s[4] = {0.f, 0.f, 0.f, 0.f}, ss[4] = {0.f, 0.f, 0.f, 0.f};
  float gg[8], lb[8];
  #pragma unroll
  for (int nt = 0; nt < 8; nt++) {
    const int c = nt * 16 + col;
    const float bsv = bias[c];
    gg[nt] = ln_g[c]; lb[nt] = ln_b[c];
    #pragma unroll
    for (int reg = 0; reg < 4; reg++) {
      const float v = acc[nt][reg] + bsv;
      acc[nt][reg] = v;
      s[reg] += v; ss[reg] += v * v;
    }
  }
  #pragma unroll
  for (int mk = 1; mk <= 8; mk <<= 1) {
    #pragma unroll
    for (int reg = 0; reg < 4; reg++) {
      s[reg]  += __shfl_xor(s[reg],  mk);
      ss[reg] += __shfl_xor(ss[reg], mk);
    }
  }
  float mu[4], rstd[4];
  #pragma unroll
  for (int reg = 0; reg < 4; reg++) {
    mu[reg] = s[reg] * (1.f / 128.f);
    const float var = ss[reg] * (1.f / 128.f) - mu[reg] * mu[reg];
    rstd[reg] = rsqrtf(var + 1e-5f);
  }
  float m8[8];
  #pragma unroll
  for (int nt = 0; nt < 8; nt++) {
    float mx = 0.f;   // ReLU floor
    #pragma unroll
    for (int reg = 0; reg < 4; reg++) {
      float v = (acc[nt][reg] - mu[reg]) * rstd[reg] * gg[nt] + lb[nt];
      v = fmaxf(v, 0.f);
      mx = fmaxf(mx, v);
    }
    m8[nt] = mx;
  }
  #pragma unroll
  for (int nt = 0; nt < 8; nt++) {
    m8[nt] = fmaxf(m8[nt], __shfl_xor(m8[nt], 16));
    m8[nt] = fmaxf(m8[nt], __shfl_xor(m8[nt], 32));
  }
  if (quad == 0) {
    #pragma unroll
    for (int nt = 0; nt < 8; nt++) wmax_s[wr][nt * 16 + col] = m8[nt];
  }
  __syncthreads();

  {
    const int v = t >> 7, c = t & 127;
    const float mx = fmaxf(wmax_s[2 * v][c], wmax_s[2 * v + 1][c]);
    pooled_s[v][c] = mx;
    const int gv = blockIdx.x * 2 + v;
    const int bo = gv >> 9, g = gv & 511;
    const int mm = g >> 6, nn = (g >> 3) & 7, tt2 = g & 7;
    const int opos = tt2 * 64 + nn * 8 + mm;
    out_all[((size_t)bo * G_ + opos) * D_ + c] = mx;
  }
  __syncthreads();

  {
    const int r = t >> 2, qs = (t & 3) * 32, v = r >> 5;
    const int pid2 = groups[m0 + r];
    float* dst = out_all + (size_t)BB * G_ * D_
               + ((size_t)(bb << 14) + (size_t)pid2) * D_ + qs;
    const float* src = &pooled_s[v][qs];
    #pragma unroll
    for (int u = 0; u < 8; u++)
      *(float4*)(dst + u * 4) = *(const float4*)(src + u * 4);
  }
}

// ---------------------------------------------------------------------------
extern "C" void kernel_launch(void* const* d_in, const int* in_sizes, int n_in,
                              void* d_out, int out_size, void* d_ws, size_t ws_size,
                              hipStream_t stream) {
  const float* inputs  = (const float*)d_in[0];
  const float* coords  = (const float*)d_in[1];
  const float* qkv_w   = (const float*)d_in[2];   // [2,128,384]
  const float* qkv_b   = (const float*)d_in[3];   // [2,384]
  const float* tbl_x   = (const float*)d_in[4];   // [2,3,50,128]
  const float* tbl_y   = (const float*)d_in[5];
  const float* tbl_z   = (const float*)d_in[6];
  const float* trans_w = (const float*)d_in[7];   // [384,128]
  const float* trans_b = (const float*)d_in[8];
  const float* ln_g    = (const float*)d_in[9];
  const float* ln_b    = (const float*)d_in[10];
  const int*   groups  = (const int*)d_in[11];    // [2,512,32] flat

  float* out = (float*)d_out;
  // workspace layout (16B-aligned chunks)
  unsigned short* Xbf  = (unsigned short*)d_ws;            // MT*128 bf16
  unsigned short* f1bf = Xbf + (size_t)MT * 128;           // MT*128 bf16
  unsigned short* f2bf = f1bf + (size_t)MT * 128;          // MT*128 bf16
  unsigned short* allfrag   = f2bf + (size_t)MT * 128;     // 2*FRAG_S
  unsigned short* transfrag = allfrag + 2 * FRAG_S;        // 96*512
  float* Tt  = (float*)(transfrag + 96 * 512);             // 2*128*256 f32
  float* Wf  = Tt + (size_t)2 * 128 * 256;                 // 2*128*256 f32
  float* bc  = Wf + (size_t)2 * 128 * 256;                 // 2*544 f32

  // ---- prep ----
  cvt_bf16<<<MT * 128 / (256 * 8), 256, 0, stream>>>(inputs, Xbf);
  prep_tt<<<256, 256, 0, stream>>>(tbl_x, tbl_y, tbl_z, Tt);
  wf_gemm<<<dim3(2, 2, 2), 256, 0, stream>>>(qkv_w, Tt, Wf);
  pack2<<<370, 64, 0, stream>>>(qkv_w, Wf, trans_w, qkv_b, Tt,
                                allfrag, transfrag, bc);

  // ---- fused layers ----
  layer_fused<<<BB * G_, 256, 0, stream>>>(
      Xbf, groups, 1, allfrag, bc, coords, f1bf);
  layer_fused<<<BB * G_, 256, 0, stream>>>(
      f1bf, groups, 0, allfrag + FRAG_S, bc + 544, coords, f2bf);

  // ---- epilogue ----
  trans_mfma<<<MT / 64, 256, 0, stream>>>(Xbf, groups, f1bf, f2bf, transfrag,
                                          trans_b, ln_g, ln_b, out);
}

// Round 7
// 180.338 us; speedup vs baseline: 5.3003x; 1.0710x over previous
//
#include <hip/hip_runtime.h>
#include <cstddef>

// Voxel encoder: B=2, N=16384, G=512 voxels x K=32 pts, d=128, S=2 layers.
// Round 7: ONE mega-kernel per voxel (everything after weight prep is
// per-voxel local): inline feats bf16 conversion -> layer0 (qkv+dk MFMA ->
// LDS, scores MFMA, shuffle softmax, PV -> f1 in LDS) -> layer1 (f2 aliased
// into qkv_s q-region) -> trans MFMA + cross-wave LN + maxpool + out/scatter.
// No f1/f2/Xbf global buffers, 4 launches total.

#define D_   128
#define VSF  0.25f
#define QSF  0.01f
#define LQ   50
#define G_   512
#define KP   32
#define BB   2
#define NP   16384
#define MT   32768
#define SCALE 0.08838834764831845f   // 1/sqrt(128)
#define NT_ALL 34           // 24 qkv tiles + 10 dk tiles (cols 0..543)
#define FRAG_S (NT_ALL * 4 * 64 * 8)   // ushorts per layer frag buffer

using short8 = __attribute__((ext_vector_type(8))) short;
using f32x4  = __attribute__((ext_vector_type(4))) float;

__device__ inline unsigned short f2bf(float x) {
  unsigned u = __builtin_bit_cast(unsigned, x);
  u += 0x7fffu + ((u >> 16) & 1u);      // round-to-nearest-even
  return (unsigned short)(u >> 16);
}
__device__ inline float bu(unsigned short h) {
  return __builtin_bit_cast(float, (unsigned)h << 16);
}
__device__ inline float blo(unsigned w) {
  return __builtin_bit_cast(float, w << 16);
}
__device__ inline float bhi(unsigned w) {
  return __builtin_bit_cast(float, w & 0xffff0000u);
}
__device__ inline short8 as_short8(uint4 v) {
  union { uint4 u; short8 s; } x; x.u = v; return x.s;
}

// ---------------------------------------------------------------------------
// Transpose the (s,1) table slices into Tt[s][e=128][c=256], c = axis*50+l,
// zero-padded for c in [150,256). grid = 256 (s*128+e), block = 256 (c).
// ---------------------------------------------------------------------------
__global__ __launch_bounds__(256) void prep_tt(
    const float* __restrict__ tbl_x, const float* __restrict__ tbl_y,
    const float* __restrict__ tbl_z, float* __restrict__ Tt)
{
  const int c = threadIdx.x;
  const int s = blockIdx.x >> 7;
  const int e = blockIdx.x & 127;
  float v = 0.f;
  if (c < 150) {
    const int axis = c / 50, l = c - axis * 50;
    const float* tb = (axis == 0 ? tbl_x : (axis == 1 ? tbl_y : tbl_z));
    v = tb[(((size_t)s * 3 + 1) * LQ + l) * D_ + e];
  }
  Tt[((size_t)(s * 128 + e)) * 256 + c] = v;
}

// ---------------------------------------------------------------------------
// Wf = Wk @ Tt (fp32, both layers). grid=(2,2,2): x=m-tile, y=n-tile, z=s.
// ---------------------------------------------------------------------------
__global__ __launch_bounds__(256) void wf_gemm(
    const float* __restrict__ qkv_w, const float* __restrict__ Tt,
    float* __restrict__ Wf)
{
  __shared__ __align__(16) float A_s[16][68];
  __shared__ __align__(16) float B_s[16][132];
  const int t  = threadIdx.x;
  const int s  = blockIdx.z;
  const float* A = qkv_w + (size_t)s * 128 * 384 + 128;   // Wk rows, lda=384
  const float* B = Tt + (size_t)s * 128 * 256;
  float* C       = Wf + (size_t)s * 128 * 256;
  const int m0 = blockIdx.x * 64;
  const int n0 = blockIdx.y * 128;
  const int r  = t >> 2;
  const int kq = (t & 3) * 4;
  const float* arow = A + (size_t)(m0 + r) * 384;
  const int kkb = t >> 4;
  const int cb  = (t & 15) * 8;
  const float* wbase = B + (size_t)kkb * 256 + n0 + cb;
  const int tx = t & 31, ty = t >> 5;

  float acc[8][4];
  #pragma unroll
  for (int i = 0; i < 8; i++)
    #pragma unroll
    for (int j = 0; j < 4; j++) acc[i][j] = 0.f;

  for (int k0 = 0; k0 < 128; k0 += 16) {
    float4 av = *(const float4*)(arow + k0 + kq);
    float4 b0 = *(const float4*)(wbase + (size_t)k0 * 256);
    float4 b1 = *(const float4*)(wbase + (size_t)k0 * 256 + 4);
    __syncthreads();
    A_s[kq + 0][r] = av.x;
    A_s[kq + 1][r] = av.y;
    A_s[kq + 2][r] = av.z;
    A_s[kq + 3][r] = av.w;
    *(float4*)&B_s[kkb][cb]     = b0;
    *(float4*)&B_s[kkb][cb + 4] = b1;
    __syncthreads();
    #pragma unroll
    for (int kk = 0; kk < 16; kk++) {
      float4 a03 = *(const float4*)&A_s[kk][ty * 8];
      float4 a47 = *(const float4*)&A_s[kk][ty * 8 + 4];
      float4 bv  = *(const float4*)&B_s[kk][tx * 4];
      float a[8] = {a03.x, a03.y, a03.z, a03.w, a47.x, a47.y, a47.z, a47.w};
      float bj[4] = {bv.x, bv.y, bv.z, bv.w};
      #pragma unroll
      for (int i = 0; i < 8; i++)
        #pragma unroll
        for (int j = 0; j < 4; j++)
          acc[i][j] += a[i] * bj[j];
    }
  }
  #pragma unroll
  for (int i = 0; i < 8; i++) {
    float4 o = {acc[i][0], acc[i][1], acc[i][2], acc[i][3]};
    *(float4*)(C + (size_t)(m0 + ty * 8 + i) * 256 + n0 + tx * 4) = o;
  }
}

// ---------------------------------------------------------------------------
// pack2: all fragment packing + combined bias in one launch. 370 blocks x 64.
// ---------------------------------------------------------------------------
__global__ __launch_bounds__(64) void pack2(
    const float* __restrict__ qkv_w, const float* __restrict__ Wf,
    const float* __restrict__ trans_w, const float* __restrict__ qkv_b,
    const float* __restrict__ Tt,
    unsigned short* __restrict__ allfrag,
    unsigned short* __restrict__ transfrag,
    float* __restrict__ bc)
{
  const int blk = blockIdx.x;
  const int lane = threadIdx.x;
  const float* B; int ldb, dstidx; unsigned short* dst; int kbase, n;
  if (blk < 192) {
    const int s = blk / 96, r = blk - s * 96;
    const int nt = r >> 2, ks = r & 3;
    B = qkv_w + (size_t)s * 128 * 384; ldb = 384;
    n = nt * 16 + (lane & 15);
    kbase = ks * 32 + ((lane >> 4) * 8);
    dst = allfrag + (size_t)s * FRAG_S;
    dstidx = nt * 4 + ks;
  } else if (blk < 272) {
    const int s = (blk - 192) / 40, r = (blk - 192) - s * 40;
    const int snt = r >> 2, ks = r & 3;
    B = Wf + (size_t)s * 32768; ldb = 256;
    n = snt * 16 + (lane & 15);
    kbase = ks * 32 + ((lane >> 4) * 8);
    dst = allfrag + (size_t)s * FRAG_S;
    dstidx = (24 + snt) * 4 + ks;
  } else if (blk < 368) {
    const int r = blk - 272;
    const int nt = r / 12, ks = r - nt * 12;
    B = trans_w; ldb = 128;
    n = nt * 16 + (lane & 15);
    kbase = ks * 32 + ((lane >> 4) * 8);
    dst = transfrag;
    dstidx = nt * 12 + ks;
  } else {
    const int s = blk - 368;
    for (int c = lane; c < 544; c += 64) {
      float v;
      if (c < 384) {
        v = qkv_b[s * 384 + c];
      } else {
        const float* bk = qkv_b + (size_t)s * 384 + 128;
        const float* T  = Tt + (size_t)s * 128 * 256 + (c - 384);
        float a = 0.f;
        #pragma unroll 4
        for (int e = 0; e < 128; e++) a += bk[e] * T[(size_t)e * 256];
        v = a;
      }
      bc[s * 544 + c] = v;
    }
    return;
  }
  unsigned v[4];
  #pragma unroll
  for (int h = 0; h < 4; h++) {
    const float x0 = B[(size_t)(kbase + 2 * h) * ldb + n];
    const float x1 = B[(size_t)(kbase + 2 * h + 1) * ldb + n];
    v[h] = f2bf(x0) | ((unsigned)f2bf(x1) << 16);
  }
  uint4 o = {v[0], v[1], v[2], v[3]};
  *(uint4*)(dst + ((size_t)dstidx * 64 + lane) * 8) = o;
}

// ---------------------------------------------------------------------------
// MEGA: one block (4 waves) per voxel; whole network per voxel.
// LDS ~59KB -> 2 blocks/CU. grid = 1024, block = 256.
// ---------------------------------------------------------------------------
__global__ __launch_bounds__(256, 2) void mega(
    const float* __restrict__ inputs,
    const float* __restrict__ coords,
    const int*   __restrict__ groups,
    const unsigned short* __restrict__ allfrag,   // 2 x FRAG_S
    const float* __restrict__ bc,                 // 2 x 544
    const unsigned short* __restrict__ transfrag, // 8 nt x 12 ks
    const float* __restrict__ trans_b, const float* __restrict__ ln_g,
    const float* __restrict__ ln_b,
    float* __restrict__ out_all)
{
  __shared__ __align__(16) unsigned short feats_s[32][136]; // pad 8: 2-way free
  __shared__ __align__(16) unsigned short f1_s[32][136];
  __shared__ __align__(16) unsigned short qkv_s[32][552];   // q|k|v|dk; f2->[0:128]
  __shared__ float sc_s[32 * 33];
  __shared__ float cs[32][4];
  __shared__ float red_s[4][16][2];
  __shared__ float wmax_s[4][128];
  __shared__ float pooled_s[128];

  const int t   = threadIdx.x;
  const int bid = blockIdx.x;
  const int b   = bid >> 9;
  const int g   = bid & 511;
  const int wv = t >> 6, lane = t & 63, quad = lane >> 4, col = lane & 15;
  const int p = t >> 3, seg = t & 7;

  // ---- stage feats (gather + fp32->bf16) and coords ----
  {
    const int pid = groups[(b << 14) + g * KP + p];
    const float* src = inputs + ((size_t)(b << 14) + (size_t)pid) * D_ + seg * 16;
    float4 a0 = *(const float4*)(src);
    float4 a1 = *(const float4*)(src + 4);
    float4 a2 = *(const float4*)(src + 8);
    float4 a3 = *(const float4*)(src + 12);
    uint4 o0, o1;
    o0.x = f2bf(a0.x) | ((unsigned)f2bf(a0.y) << 16);
    o0.y = f2bf(a0.z) | ((unsigned)f2bf(a0.w) << 16);
    o0.z = f2bf(a1.x) | ((unsigned)f2bf(a1.y) << 16);
    o0.w = f2bf(a1.z) | ((unsigned)f2bf(a1.w) << 16);
    o1.x = f2bf(a2.x) | ((unsigned)f2bf(a2.y) << 16);
    o1.y = f2bf(a2.z) | ((unsigned)f2bf(a2.w) << 16);
    o1.z = f2bf(a3.x) | ((unsigned)f2bf(a3.y) << 16);
    o1.w = f2bf(a3.z) | ((unsigned)f2bf(a3.w) << 16);
    *(uint4*)&feats_s[p][seg * 16]     = o0;
    *(uint4*)&feats_s[p][seg * 16 + 8] = o1;
  }
  if (t < 32) {
    const int pid = groups[(b << 14) + g * KP + t];
    const float* cp = coords + ((size_t)(b << 14) + (size_t)pid) * 3;
    cs[t][0] = cp[0]; cs[t][1] = cp[1]; cs[t][2] = cp[2];
  }
  __syncthreads();

  // ---- two attention layers ----
  const int starts[4] = {0, 9, 18, 26};
  const int start = starts[wv];
  const int cnt = (wv < 2) ? 9 : 8;
  const int ihalf = wv >> 1, jhalf = wv & 1;

  for (int layer = 0; layer < 2; layer++) {
    const unsigned short (*Asrc)[136] = (layer == 0) ? feats_s : f1_s;
    const uint4* fr = (const uint4*)(allfrag + (size_t)layer * FRAG_S) + lane;
    const float* bcl = bc + layer * 544;

    // Phase A: qkv+dk GEMM (32 rows x 544 cols, K=128), A from LDS
    f32x4 acc[9][2];
    #pragma unroll
    for (int u = 0; u < 9; u++) {
      acc[u][0] = (f32x4){0.f, 0.f, 0.f, 0.f};
      acc[u][1] = (f32x4){0.f, 0.f, 0.f, 0.f};
    }
    #pragma unroll
    for (int ks = 0; ks < 4; ks++) {
      short8 av0 = as_short8(*(const uint4*)&Asrc[col][ks * 32 + quad * 8]);
      short8 av1 = as_short8(*(const uint4*)&Asrc[16 + col][ks * 32 + quad * 8]);
      #pragma unroll
      for (int u = 0; u < 9; u++) {
        if (u < cnt) {
          short8 bv = as_short8(fr[((start + u) * 4 + ks) * 64]);
          acc[u][0] = __builtin_amdgcn_mfma_f32_16x16x32_bf16(av0, bv, acc[u][0], 0, 0, 0);
          acc[u][1] = __builtin_amdgcn_mfma_f32_16x16x32_bf16(av1, bv, acc[u][1], 0, 0, 0);
        }
      }
    }
    #pragma unroll
    for (int u = 0; u < 9; u++) {
      if (u < cnt) {
        const int cc = (start + u) * 16 + col;
        const float bsv = bcl[cc];
        #pragma unroll
        for (int rt = 0; rt < 2; rt++)
          #pragma unroll
          for (int reg = 0; reg < 4; reg++)
            qkv_s[rt * 16 + quad * 4 + reg][cc] = f2bf(acc[u][rt][reg] + bsv);
      }
    }
    __syncthreads();

    // scores via MFMA from LDS frags
    f32x4 sacc = {0.f, 0.f, 0.f, 0.f};
    #pragma unroll
    for (int ks = 0; ks < 4; ks++) {
      short8 qv = as_short8(*(const uint4*)&qkv_s[ihalf * 16 + col][ks * 32 + quad * 8]);
      short8 kv = as_short8(*(const uint4*)&qkv_s[jhalf * 16 + col][128 + ks * 32 + quad * 8]);
      sacc = __builtin_amdgcn_mfma_f32_16x16x32_bf16(qv, kv, sacc, 0, 0, 0);
    }
    {
      const int j = jhalf * 16 + col;
      const float cjx = cs[j][0], cjy = cs[j][1], cjz = cs[j][2];
      #pragma unroll
      for (int reg = 0; reg < 4; reg++) {
        const int i = ihalf * 16 + quad * 4 + reg;
        const float dx = cs[i][0] - cjx;
        const float dy = cs[i][1] - cjy;
        const float dz = cs[i][2] - cjz;
        int ix = (int)floorf((dx + VSF) / QSF);
        int iy = (int)floorf((dy + VSF) / QSF);
        int iz = (int)floorf((dz + VSF) / QSF);
        ix = ix < 0 ? 0 : (ix > 49 ? 49 : ix);
        iy = iy < 0 ? 0 : (iy > 49 ? 49 : iy);
        iz = iz < 0 ? 0 : (iz > 49 ? 49 : iz);
        const unsigned short* dki = &qkv_s[i][384];
        const float biasv = bu(dki[ix]) + bu(dki[50 + iy]) + bu(dki[100 + iz]);
        sc_s[i * 33 + j] = (sacc[reg] + biasv) * SCALE;
      }
    }
    __syncthreads();

    // softmax: 8 threads per row, shuffle over the 8-lane group
    {
      float vals[4];
      float lm = -1e30f;
      #pragma unroll
      for (int u = 0; u < 4; u++) {
        vals[u] = sc_s[p * 33 + seg + u * 8];
        lm = fmaxf(lm, vals[u]);
      }
      lm = fmaxf(lm, __shfl_xor(lm, 1));
      lm = fmaxf(lm, __shfl_xor(lm, 2));
      lm = fmaxf(lm, __shfl_xor(lm, 4));
      float ls = 0.f;
      #pragma unroll
      for (int u = 0; u < 4; u++) { vals[u] = __expf(vals[u] - lm); ls += vals[u]; }
      ls += __shfl_xor(ls, 1);
      ls += __shfl_xor(ls, 2);
      ls += __shfl_xor(ls, 4);
      const float inv = 1.f / ls;
      #pragma unroll
      for (int u = 0; u < 4; u++) sc_s[p * 33 + seg + u * 8] = vals[u] * inv;
    }
    __syncthreads();

    // PV (fp32 VALU); layer0 -> f1_s, layer1 -> qkv_s[:,0:128] (f2)
    {
      const int es = seg * 16;
      float a2[16];
      #pragma unroll
      for (int k = 0; k < 16; k++) a2[k] = 0.f;
      #pragma unroll 4
      for (int j = 0; j < 32; j++) {
        const float a = sc_s[p * 33 + j];
        const uint4 u0 = *(const uint4*)&qkv_s[j][256 + es];
        const uint4 u1 = *(const uint4*)&qkv_s[j][256 + es + 8];
        a2[0]  += a * blo(u0.x); a2[1]  += a * bhi(u0.x);
        a2[2]  += a * blo(u0.y); a2[3]  += a * bhi(u0.y);
        a2[4]  += a * blo(u0.z); a2[5]  += a * bhi(u0.z);
        a2[6]  += a * blo(u0.w); a2[7]  += a * bhi(u0.w);
        a2[8]  += a * blo(u1.x); a2[9]  += a * bhi(u1.x);
        a2[10] += a * blo(u1.y); a2[11] += a * bhi(u1.y);
        a2[12] += a * blo(u1.z); a2[13] += a * bhi(u1.z);
        a2[14] += a * blo(u1.w); a2[15] += a * bhi(u1.w);
      }
      uint4 o0, o1;
      o0.x = f2bf(a2[0])  | ((unsigned)f2bf(a2[1])  << 16);
      o0.y = f2bf(a2[2])  | ((unsigned)f2bf(a2[3])  << 16);
      o0.z = f2bf(a2[4])  | ((unsigned)f2bf(a2[5])  << 16);
      o0.w = f2bf(a2[6])  | ((unsigned)f2bf(a2[7])  << 16);
      o1.x = f2bf(a2[8])  | ((unsigned)f2bf(a2[9])  << 16);
      o1.y = f2bf(a2[10]) | ((unsigned)f2bf(a2[11]) << 16);
      o1.z = f2bf(a2[12]) | ((unsigned)f2bf(a2[13]) << 16);
      o1.w = f2bf(a2[14]) | ((unsigned)f2bf(a2[15]) << 16);
      unsigned short* dst = (layer == 0) ? &f1_s[p][es] : &qkv_s[p][es];
      *(uint4*)dst       = o0;
      *(uint4*)(dst + 8) = o1;
    }
    __syncthreads();
  }

  // ---- trans GEMM (K=384: feats|f1|f2) + LN + ReLU + maxpool + outputs ----
  const int mtile = wv & 1, colhalf = wv >> 1;
  f32x4 tacc[4];
  #pragma unroll
  for (int u = 0; u < 4; u++) tacc[u] = (f32x4){0.f, 0.f, 0.f, 0.f};
  const uint4* tf = (const uint4*)transfrag + lane;
  #pragma unroll
  for (int ks = 0; ks < 12; ks++) {
    const unsigned short* ar =
        (ks < 4) ? &feats_s[mtile * 16 + col][(ks & 3) * 32 + quad * 8]
      : (ks < 8) ? &f1_s[mtile * 16 + col][(ks & 3) * 32 + quad * 8]
                 : &qkv_s[mtile * 16 + col][(ks & 3) * 32 + quad * 8];
    short8 av = as_short8(*(const uint4*)ar);
    #pragma unroll
    for (int u = 0; u < 4; u++) {
      const int nt = colhalf * 4 + u;
      short8 bv = as_short8(tf[(nt * 12 + ks) * 64]);
      tacc[u] = __builtin_amdgcn_mfma_f32_16x16x32_bf16(av, bv, tacc[u], 0, 0, 0);
    }
  }
  // bias + LN partial stats (64 cols per wave)
  float s[4] = {0.f, 0.f, 0.f, 0.f}, ssq[4] = {0.f, 0.f, 0.f, 0.f};
  float gg[4], lb[4];
  #pragma unroll
  for (int u = 0; u < 4; u++) {
    const int c = (colhalf * 4 + u) * 16 + col;
    const float bsv = trans_b[c];
    gg[u] = ln_g[c]; lb[u] = ln_b[c];
    #pragma unroll
    for (int reg = 0; reg < 4; reg++) {
      const float v = tacc[u][reg] + bsv;
      tacc[u][reg] = v;
      s[reg] += v; ssq[reg] += v * v;
    }
  }
  #pragma unroll
  for (int mk = 1; mk <= 8; mk <<= 1) {
    #pragma unroll
    for (int reg = 0; reg < 4; reg++) {
      s[reg]   += __shfl_xor(s[reg],   mk);
      ssq[reg] += __shfl_xor(ssq[reg], mk);
    }
  }
  if (col == 0) {
    #pragma unroll
    for (int reg = 0; reg < 4; reg++) {
      red_s[wv][quad * 4 + reg][0] = s[reg];
      red_s[wv][quad * 4 + reg][1] = ssq[reg];
    }
  }
  __syncthreads();
  const int partner = wv ^ 2;   // same mtile, other colhalf
  float mu[4], rstd[4];
  #pragma unroll
  for (int reg = 0; reg < 4; reg++) {
    const float st  = s[reg]   + red_s[partner][quad * 4 + reg][0];
    const float sst = ssq[reg] + red_s[partner][quad * 4 + reg][1];
    mu[reg] = st * (1.f / 128.f);
    const float var = sst * (1.f / 128.f) - mu[reg] * mu[reg];
    rstd[reg] = rsqrtf(var + 1e-5f);
  }
  // LN + ReLU + column max over this wave's 16 rows
  float cm[4];
  #pragma unroll
  for (int u = 0; u < 4; u++) {
    float mx = 0.f;   // ReLU floor
    #pragma unroll
    for (int reg = 0; reg < 4; reg++) {
      float v = (tacc[u][reg] - mu[reg]) * rstd[reg] * gg[u] + lb[u];
      v = fmaxf(v, 0.f);
      mx = fmaxf(mx, v);
    }
    cm[u] = mx;
  }
  #pragma unroll
  for (int u = 0; u < 4; u++) {
    cm[u] = fmaxf(cm[u], __shfl_xor(cm[u], 16));
    cm[u] = fmaxf(cm[u], __shfl_xor(cm[u], 32));
  }
  if (quad == 0) {
    #pragma unroll
    for (int u = 0; u < 4; u++)
      wmax_s[wv][(colhalf * 4 + u) * 16 + col] = cm[u];
  }
  __syncthreads();

  // pooled = max over both mtiles; grid-reordered out write
  if (t < 128) {
    const int c = t;
    const int base = (c >> 6) * 2;   // c<64 -> waves 0,1 ; else waves 2,3
    const float mx = fmaxf(wmax_s[base][c], wmax_s[base + 1][c]);
    pooled_s[c] = mx;
    const int mm = g >> 6, nn = (g >> 3) & 7, tt2 = g & 7;
    const int opos = tt2 * 64 + nn * 8 + mm;
    out_all[((size_t)b * G_ + opos) * D_ + c] = mx;
  }
  __syncthreads();

  // scatter pooled to every point (for_ret)
  {
    const int pid = groups[(b << 14) + g * KP + p];
    float* dst = out_all + (size_t)BB * G_ * D_
               + ((size_t)(b << 14) + (size_t)pid) * D_ + seg * 16;
    #pragma unroll
    for (int u = 0; u < 4; u++)
      *(float4*)(dst + u * 4) = *(const float4*)&pooled_s[seg * 16 + u * 4];
  }
}

// ---------------------------------------------------------------------------
extern "C" void kernel_launch(void* const* d_in, const int* in_sizes, int n_in,
                              void* d_out, int out_size, void* d_ws, size_t ws_size,
                              hipStream_t stream) {
  const float* inputs  = (const float*)d_in[0];
  const float* coords  = (const float*)d_in[1];
  const float* qkv_w   = (const float*)d_in[2];   // [2,128,384]
  const float* qkv_b   = (const float*)d_in[3];   // [2,384]
  const float* tbl_x   = (const float*)d_in[4];   // [2,3,50,128]
  const float* tbl_y   = (const float*)d_in[5];
  const float* tbl_z   = (const float*)d_in[6];
  const float* trans_w = (const float*)d_in[7];   // [384,128]
  const float* trans_b = (const float*)d_in[8];
  const float* ln_g    = (const float*)d_in[9];
  const float* ln_b    = (const float*)d_in[10];
  const int*   groups  = (const int*)d_in[11];    // [2,512,32] flat

  float* out = (float*)d_out;
  unsigned short* allfrag   = (unsigned short*)d_ws;       // 2*FRAG_S
  unsigned short* transfrag = allfrag + 2 * FRAG_S;        // 96*512
  float* Tt  = (float*)(transfrag + 96 * 512);             // 2*128*256 f32
  float* Wf  = Tt + (size_t)2 * 128 * 256;                 // 2*128*256 f32
  float* bc  = Wf + (size_t)2 * 128 * 256;                 // 2*544 f32

  // ---- prep (weights only) ----
  prep_tt<<<256, 256, 0, stream>>>(tbl_x, tbl_y, tbl_z, Tt);
  wf_gemm<<<dim3(2, 2, 2), 256, 0, stream>>>(qkv_w, Tt, Wf);
  pack2<<<370, 64, 0, stream>>>(qkv_w, Wf, trans_w, qkv_b, Tt,
                                allfrag, transfrag, bc);

  // ---- whole network, one kernel ----
  mega<<<BB * G_, 256, 0, stream>>>(inputs, coords, groups, allfrag, bc,
                                    transfrag, trans_b, ln_g, ln_b, out);
}